// Round 16
// baseline (346.148 us; speedup 1.0000x reference)
//
#include <hip/hip_runtime.h>
#include <hip/hip_bf16.h>
#include <math.h>

#define CDIM 768
#define HDIM 3072
#define NROWS 4096   // B*T
#define TSEQ 2048
#define NHEAD 12
#define KVSPLIT 4
#define KVLEN (TSEQ / KVSPLIT)   // 512 rows per part

typedef unsigned short u16;
typedef unsigned int   u32;
typedef __attribute__((ext_vector_type(8))) short short8;
typedef __attribute__((ext_vector_type(4))) float f32x4;

// 1/sqrt(64) * log2(e): folds the softmax ln->log2 conversion into Q
#define QSCALE 0.18033688011112042f

static __device__ __forceinline__ u16 f2bf(float f) {
    u32 x = __float_as_uint(f);
    x += 0x7fffu + ((x >> 16) & 1u);
    return (u16)(x >> 16);
}
static __device__ __forceinline__ float bf2f(u16 x) {
    return __uint_as_float((u32)x << 16);
}
static __device__ __forceinline__ u32 cvt_pk_bf16(float lo, float hi) {
    u32 r;
    asm("v_cvt_pk_bf16_f32 %0, %1, %2" : "=v"(r) : "v"(lo), "v"(hi));
    return r;
}

#define GLL16(g, l)                                                            \
    __builtin_amdgcn_global_load_lds(                                          \
        (const __attribute__((address_space(1))) void*)(g),                    \
        (__attribute__((address_space(3))) void*)(l), 16, 0, 0)

// ---------------------------------------------------------------- packed pre-work helpers
// smem: at least 32*33 floats (4224 B), reused by all branches.
static __device__ void do_cvt(int blk, const float* __restrict__ in,
                              u16* __restrict__ out) {
    const int i = blk * 256 + threadIdx.x;   // float4 index, exact multiple
    float4 v = ((const float4*)in)[i];
    ushort4 o;
    o.x = f2bf(v.x); o.y = f2bf(v.y); o.z = f2bf(v.z); o.w = f2bf(v.w);
    ((ushort4*)out)[i] = o;
}

static __device__ void do_ln(int row, const float* __restrict__ x,
                             const float* __restrict__ g,
                             const float* __restrict__ bta,
                             u16* __restrict__ out, float* red) {
    const int tid = threadIdx.x;
    const float* xr = x + (size_t)row * CDIM;
    float v0 = xr[tid], v1 = xr[tid + 256], v2 = xr[tid + 512];
    float s = v0 + v1 + v2;
#pragma unroll
    for (int m = 1; m < 64; m <<= 1) s += __shfl_xor(s, m);
    if ((tid & 63) == 0) red[tid >> 6] = s;
    __syncthreads();
    const float mu = (red[0] + red[1] + red[2] + red[3]) * (1.f / CDIM);
    const float d0 = v0 - mu, d1 = v1 - mu, d2 = v2 - mu;
    float q = d0 * d0 + d1 * d1 + d2 * d2;
#pragma unroll
    for (int m = 1; m < 64; m <<= 1) q += __shfl_xor(q, m);
    if ((tid & 63) == 0) red[4 + (tid >> 6)] = q;
    __syncthreads();
    const float var = (red[4] + red[5] + red[6] + red[7]) * (1.f / CDIM);
    const float rstd = rsqrtf(var + 1e-5f);
    u16* orow = out + (size_t)row * CDIM;
    orow[tid]       = f2bf(d0 * rstd * g[tid]       + bta[tid]);
    orow[tid + 256] = f2bf(d1 * rstd * g[tid + 256] + bta[tid + 256]);
    orow[tid + 512] = f2bf(d2 * rstd * g[tid + 512] + bta[tid + 512]);
}

static __device__ void do_wt(int bx, int by, const float* __restrict__ w,
                             u16* __restrict__ wt, int K, int N, float* t /*32x33*/) {
    const int n0 = bx * 32, k0 = by * 32;
    const int tx = threadIdx.x & 31, ty = threadIdx.x >> 5;
#pragma unroll
    for (int i = ty; i < 32; i += 8)
        t[i * 33 + tx] = w[(size_t)(k0 + i) * N + n0 + tx];
    __syncthreads();
#pragma unroll
    for (int i = ty; i < 32; i += 8)
        wt[(size_t)(n0 + i) * K + k0 + tx] = f2bf(t[tx * 33 + i]);
}

// pre1: cvt_copy (3072) | LN1 (4096) | SA wtrans x4 (2304)
struct Pre1 {
    const float* ctx; u16* ctxb;
    const float* x; const float* g; const float* bta; u16* lnout;
    const float* w[4]; u16* wt[4];
};
__launch_bounds__(256)
__global__ void pre1_kernel(Pre1 p) {
    __shared__ float smem[32 * 33];
    int bid = blockIdx.x;
    if (bid < 3072) { do_cvt(bid, p.ctx, p.ctxb); return; }
    bid -= 3072;
    if (bid < 4096) { do_ln(bid, p.x, p.g, p.bta, p.lnout, smem); return; }
    bid -= 4096;
    const int z = bid / 576, rem = bid % 576;
    do_wt(rem % 24, rem / 24, p.w[z], p.wt[z], CDIM, CDIM, smem);
}

// pre2: LN (4096) | wtrans x4 (2304)
struct Pre2 {
    const float* x; const float* g; const float* bta; u16* lnout;
    const float* w[4]; u16* wt[4];
};
__launch_bounds__(256)
__global__ void pre2_kernel(Pre2 p) {
    __shared__ float smem[32 * 33];
    int bid = blockIdx.x;
    if (bid < 4096) { do_ln(bid, p.x, p.g, p.bta, p.lnout, smem); return; }
    bid -= 4096;
    const int z = bid / 576, rem = bid % 576;
    do_wt(rem % 24, rem / 24, p.w[z], p.wt[z], CDIM, CDIM, smem);
}

// pre3: LN3 (4096) | m_w1^T (2304: 96x24) | m_w2^T (2304: 24x96)
struct Pre3 {
    const float* x; const float* g; const float* bta; u16* lnout;
    const float* w1; u16* wt1;
    const float* w2; u16* wt2;
};
__launch_bounds__(256)
__global__ void pre3_kernel(Pre3 p) {
    __shared__ float smem[32 * 33];
    int bid = blockIdx.x;
    if (bid < 4096) { do_ln(bid, p.x, p.g, p.bta, p.lnout, smem); return; }
    bid -= 4096;
    if (bid < 2304) { do_wt(bid % 96, bid / 96, p.w1, p.wt1, CDIM, HDIM, smem); return; }
    bid -= 2304;
    do_wt(bid % 24, bid / 24, p.w2, p.wt2, HDIM, CDIM, smem);
}

// ---------------------------------------------------------------- GEMM (R12-verified)
struct GemmArgs {
    const u16* A[3];
    const u16* BT[3];
    const float* bias[3];
    const float* res[3];
    void* out[3];
    float alpha[3];
    int M, N, K;
};

// EPI: 0 = (s+bias)*alpha -> bf16 ; 1 = res + s + bias -> f32 ; 2 = gelu -> bf16
template <int EPI, int BM, int BN = 128>
__launch_bounds__(256)
__global__ void gemm_bt(GemmArgs ga) {
    constexpr int MF = BM / 32, NF = BN / 32;
    __shared__ u16 Abuf[BM * 32];
    __shared__ u16 Bbuf[BN * 32];
    const int z = blockIdx.z;
    const u16* __restrict__ A  = ga.A[z];
    const u16* __restrict__ BT = ga.BT[z];
    const float* __restrict__ bias = ga.bias[z];
    const float* __restrict__ res  = ga.res[z];
    void* outv = ga.out[z];
    const float alpha = ga.alpha[z];
    const int N = ga.N, K = ga.K;

    const int tid = threadIdx.x;
    const int lane = tid & 63, w = tid >> 6;
    const int m0 = blockIdx.x * BM, n0 = blockIdx.y * BN;
    const int wr = (w >> 1) * (BM / 2), wc = (w & 1) * (BN / 2);
    const int lr = lane & 15, lc = lane >> 4;

    const int srowA = (BM == 128) ? (w * 32 + (lane >> 2)) : (tid >> 2);
    const int srowB = (BN == 128) ? (w * 32 + (lane >> 2)) : (tid >> 2);
    const int scol = (lane & 3) * 8;
    const u16* Ag = A + (size_t)(m0 + srowA) * K + scol;
    const u16* Bg = BT + (size_t)(n0 + srowB) * K + scol;
    char* Ab = (char*)Abuf + w * (BM == 128 ? 2048 : 1024);
    char* Bb = (char*)Bbuf + w * (BN == 128 ? 2048 : 1024);

    f32x4 acc[MF][NF];
#pragma unroll
    for (int m = 0; m < MF; ++m)
#pragma unroll
        for (int n = 0; n < NF; ++n) acc[m][n] = (f32x4){0.f, 0.f, 0.f, 0.f};

    const int nk = K >> 5;
    for (int kt = 0; kt < nk; ++kt) {
        const int ko = kt * 32;
        GLL16(Ag + ko, Ab);
        if constexpr (BM == 128) GLL16(Ag + 16 * K + ko, Ab + 1024);
        GLL16(Bg + ko, Bb);
        if constexpr (BN == 128) GLL16(Bg + 16 * K + ko, Bb + 1024);
        __syncthreads();
        short8 af[MF], bfv[NF];
#pragma unroll
        for (int m = 0; m < MF; ++m)
            af[m] = *(const short8*)((const char*)Abuf +
                                     (size_t)(wr + m * 16 + lr) * 64 + lc * 16);
#pragma unroll
        for (int n = 0; n < NF; ++n)
            bfv[n] = *(const short8*)((const char*)Bbuf +
                                      (size_t)(wc + n * 16 + lr) * 64 + lc * 16);
#pragma unroll
        for (int m = 0; m < MF; ++m)
#pragma unroll
            for (int n = 0; n < NF; ++n)
                acc[m][n] = __builtin_amdgcn_mfma_f32_16x16x32_bf16(
                    af[m], bfv[n], acc[m][n], 0, 0, 0);
        __syncthreads();
    }

#pragma unroll
    for (int n = 0; n < NF; ++n) {
        const int gc = n0 + wc + n * 16 + lr;
        const float bs = bias[gc];
#pragma unroll
        for (int m = 0; m < MF; ++m) {
            const int gr = m0 + wr + m * 16 + lc * 4;
#pragma unroll
            for (int r = 0; r < 4; ++r) {
                float v = (acc[m][n][r] + bs) * alpha;
                const size_t idx = (size_t)(gr + r) * N + gc;
                if constexpr (EPI == 0) {
                    ((u16*)outv)[idx] = f2bf(v);
                } else if constexpr (EPI == 1) {
                    ((float*)outv)[idx] = res[idx] + v;
                } else {
                    float gel = 0.5f * v * (1.0f + erff(v * 0.70710678118654752f));
                    ((u16*)outv)[idx] = f2bf(gel);
                }
            }
        }
    }
}

// ---------------------------------------------------------------- attention helpers
static __device__ __forceinline__ void softmax_pack(f32x4 sf[4], float& mrow,
                                                    float& lrow, f32x4 oacc[4],
                                                    short8& p0, short8& p1) {
    float pm;
    {
        float a0 = fmaxf(fmaxf(sf[0][0], sf[0][1]), fmaxf(sf[0][2], sf[0][3]));
        float a1 = fmaxf(fmaxf(sf[1][0], sf[1][1]), fmaxf(sf[1][2], sf[1][3]));
        float a2 = fmaxf(fmaxf(sf[2][0], sf[2][1]), fmaxf(sf[2][2], sf[2][3]));
        float a3 = fmaxf(fmaxf(sf[3][0], sf[3][1]), fmaxf(sf[3][2], sf[3][3]));
        pm = fmaxf(fmaxf(a0, a1), fmaxf(a2, a3));
        pm = fmaxf(pm, __shfl_xor(pm, 16));
        pm = fmaxf(pm, __shfl_xor(pm, 32));
    }
    // defer-max: only rescale when some q-row's max grew (wave-uniform)
    if (!__all(pm <= mrow)) {
        const float mn = fmaxf(mrow, pm);
        const float corr = exp2f(mrow - mn);
        mrow = mn;
        lrow *= corr;
#pragma unroll
        for (int fd = 0; fd < 4; ++fd)
#pragma unroll
            for (int r = 0; r < 4; ++r) oacc[fd][r] *= corr;
    }
#pragma unroll
    for (int fn = 0; fn < 4; ++fn)
#pragma unroll
        for (int r = 0; r < 4; ++r) sf[fn][r] = exp2f(sf[fn][r] - mrow);
    float rs;
    {
        float s0 = (sf[0][0] + sf[0][1]) + (sf[0][2] + sf[0][3]);
        float s1 = (sf[1][0] + sf[1][1]) + (sf[1][2] + sf[1][3]);
        float s2 = (sf[2][0] + sf[2][1]) + (sf[2][2] + sf[2][3]);
        float s3 = (sf[3][0] + sf[3][1]) + (sf[3][2] + sf[3][3]);
        rs = (s0 + s1) + (s2 + s3);
        rs += __shfl_xor(rs, 16);
        rs += __shfl_xor(rs, 32);
    }
    lrow += rs;
    int4 pw0, pw1;
    pw0.x = cvt_pk_bf16(sf[0][0], sf[0][1]);
    pw0.y = cvt_pk_bf16(sf[0][2], sf[0][3]);
    pw0.z = cvt_pk_bf16(sf[1][0], sf[1][1]);
    pw0.w = cvt_pk_bf16(sf[1][2], sf[1][3]);
    pw1.x = cvt_pk_bf16(sf[2][0], sf[2][1]);
    pw1.y = cvt_pk_bf16(sf[2][2], sf[2][3]);
    pw1.z = cvt_pk_bf16(sf[3][0], sf[3][1]);
    pw1.w = cvt_pk_bf16(sf[3][2], sf[3][3]);
    p0 = *(short8*)&pw0;
    p1 = *(short8*)&pw1;
}

// ---------------------------------------------------------------- attention (split-KV, 128q/block)
__launch_bounds__(256, 4)
__global__ void attn_split(const u16* __restrict__ Qb, const u16* __restrict__ Kb,
                           const u16* __restrict__ Vb, u16* __restrict__ Opart,
                           float2* __restrict__ ml) {
    __shared__ u16 Klds[64 * 72];
    __shared__ u16 Vt[64 * 72];
    const int tid = threadIdx.x;
    const int lane = tid & 63, w = tid >> 6;
    const int lr = lane & 15, lc = lane >> 4;
    const int b = blockIdx.y / NHEAD, h = blockIdx.y % NHEAD;
    const int z = blockIdx.z;
    const size_t qrowA = (size_t)b * TSEQ + blockIdx.x * 128 + w * 16;
    const size_t qrowB = qrowA + 64;
    const size_t krow0 = (size_t)b * TSEQ + (size_t)z * KVLEN;
    const int hc = h * 64;

    short8 qa0, qa1, qb0, qb1;
    {
        const u16* qp = Qb + (qrowA + lr) * CDIM + hc + lc * 8;
        qa0 = *(const short8*)qp;
        qa1 = *(const short8*)(qp + 32);
        const u16* qp2 = Qb + (qrowB + lr) * CDIM + hc + lc * 8;
        qb0 = *(const short8*)qp2;
        qb1 = *(const short8*)(qp2 + 32);
    }
    f32x4 oaccA[4], oaccB[4];
#pragma unroll
    for (int r = 0; r < 4; ++r) {
        oaccA[r] = (f32x4){0.f, 0.f, 0.f, 0.f};
        oaccB[r] = (f32x4){0.f, 0.f, 0.f, 0.f};
    }
    float mA = -3e38f, lA = 0.f, mB = -3e38f, lB = 0.f;

    const int stg_r = tid >> 2, stg_s = tid & 3;
    const u16* kg = Kb + (krow0 + stg_r) * CDIM + hc + stg_s * 16;
    const u16* vg = Vb + (krow0 + stg_r) * CDIM + hc + stg_s * 16;
    uint4 ka0 = *(const uint4*)kg, ka1 = *(const uint4*)(kg + 8);
    uint4 va0 = *(const uint4*)vg, va1 = *(const uint4*)(vg + 8);
    const int sig = ((stg_r >> 5) << 5) + (((stg_r >> 2) & 3) << 3) +
                    (((stg_r >> 4) & 1) << 2) + (stg_r & 3);
    char* vdst = (char*)Vt + ((2 * sig) ^ (stg_s << 5)) +
                 (size_t)(stg_s * 16) * 144;

    for (int kt = 0; kt < KVLEN / 64; ++kt) {
        __syncthreads();
        {
            *(uint4*)&Klds[stg_r * 72 + stg_s * 16]     = ka0;
            *(uint4*)&Klds[stg_r * 72 + stg_s * 16 + 8] = ka1;
            u16 tmp[16];
            *(uint4*)(tmp)     = va0;
            *(uint4*)(tmp + 8) = va1;
#pragma unroll
            for (int j = 0; j < 16; ++j)
                *(u16*)(vdst + (size_t)j * 144) = tmp[j];
        }
        if (kt < KVLEN / 64 - 1) {
            kg += 64 * CDIM; vg += 64 * CDIM;
            ka0 = *(const uint4*)kg; ka1 = *(const uint4*)(kg + 8);
            va0 = *(const uint4*)vg; va1 = *(const uint4*)(vg + 8);
        }
        __syncthreads();

        // S^T = K * Q^T for both q-groups; each K fragment read used twice
        f32x4 sfA[4], sfB[4];
#pragma unroll
        for (int fn = 0; fn < 4; ++fn) {
            const u16* kr = &Klds[(lr + fn * 16) * 72 + lc * 8];
            short8 kb0 = *(const short8*)kr;
            short8 kb1 = *(const short8*)(kr + 32);
            f32x4 t = (f32x4){0.f, 0.f, 0.f, 0.f};
            t = __builtin_amdgcn_mfma_f32_16x16x32_bf16(kb0, qa0, t, 0, 0, 0);
            t = __builtin_amdgcn_mfma_f32_16x16x32_bf16(kb1, qa1, t, 0, 0, 0);
            sfA[fn] = t;
            f32x4 u = (f32x4){0.f, 0.f, 0.f, 0.f};
            u = __builtin_amdgcn_mfma_f32_16x16x32_bf16(kb0, qb0, u, 0, 0, 0);
            u = __builtin_amdgcn_mfma_f32_16x16x32_bf16(kb1, qb1, u, 0, 0, 0);
            sfB[fn] = u;
        }

        short8 pA0, pA1, pB0, pB1;
        softmax_pack(sfA, mA, lA, oaccA, pA0, pA1);
        softmax_pack(sfB, mB, lB, oaccB, pB0, pB1);

        // O^T += V^T * P^T ; each V fragment read used twice
#pragma unroll
        for (int fd = 0; fd < 4; ++fd) {
            const char* vtb = (const char*)Vt + (size_t)(lr + fd * 16) * 144;
            short8 vb0 = *(const short8*)(vtb + ((lc * 16) ^ (fd * 32)));
            short8 vb1 = *(const short8*)(vtb + ((lc * 16 + 64) ^ (fd * 32)));
            oaccA[fd] = __builtin_amdgcn_mfma_f32_16x16x32_bf16(vb0, pA0, oaccA[fd], 0, 0, 0);
            oaccA[fd] = __builtin_amdgcn_mfma_f32_16x16x32_bf16(vb1, pA1, oaccA[fd], 0, 0, 0);
            oaccB[fd] = __builtin_amdgcn_mfma_f32_16x16x32_bf16(vb0, pB0, oaccB[fd], 0, 0, 0);
            oaccB[fd] = __builtin_amdgcn_mfma_f32_16x16x32_bf16(vb1, pB1, oaccB[fd], 0, 0, 0);
        }
    }

    // epilogue: UNNORMALIZED bf16 partials + (m,l) for both groups
    u16* oA = Opart + (size_t)z * NROWS * CDIM + (qrowA + lr) * CDIM + hc + lc * 4;
    u16* oB = Opart + (size_t)z * NROWS * CDIM + (qrowB + lr) * CDIM + hc + lc * 4;
#pragma unroll
    for (int fd = 0; fd < 4; ++fd) {
        ushort4 o;
        o.x = f2bf(oaccA[fd][0]); o.y = f2bf(oaccA[fd][1]);
        o.z = f2bf(oaccA[fd][2]); o.w = f2bf(oaccA[fd][3]);
        *(ushort4*)(oA + fd * 16) = o;
        o.x = f2bf(oaccB[fd][0]); o.y = f2bf(oaccB[fd][1]);
        o.z = f2bf(oaccB[fd][2]); o.w = f2bf(oaccB[fd][3]);
        *(ushort4*)(oB + fd * 16) = o;
    }
    if (lc == 0) {
        ml[((size_t)z * NROWS + qrowA + lr) * NHEAD + h] = (float2){mA, lA};
        ml[((size_t)z * NROWS + qrowB + lr) * NHEAD + h] = (float2){mB, lB};
    }
}

// ---------------------------------------------------------------- merge (4 parts)
__launch_bounds__(256)
__global__ void attn_merge4(const u16* __restrict__ P, const float2* __restrict__ ml,
                            u16* __restrict__ out) {
    const int i4 = blockIdx.x * 256 + threadIdx.x;   // 4-elem chunk index
    const size_t base = (size_t)i4 * 4;
    const int row = (int)(base / CDIM);
    const int head = (int)(base - (size_t)row * CDIM) >> 6;
    float2 a[KVSPLIT];
    float M = -3e38f;
#pragma unroll
    for (int z = 0; z < KVSPLIT; ++z) {
        a[z] = ml[((size_t)z * NROWS + row) * NHEAD + head];
        M = fmaxf(M, a[z].x);
    }
    float den = 0.f, e[KVSPLIT];
#pragma unroll
    for (int z = 0; z < KVSPLIT; ++z) {
        e[z] = exp2f(a[z].x - M);
        den += a[z].y * e[z];
    }
    const float rden = 1.f / den;
    float o0 = 0.f, o1 = 0.f, o2 = 0.f, o3 = 0.f;
#pragma unroll
    for (int z = 0; z < KVSPLIT; ++z) {
        ushort4 p = *(const ushort4*)(P + (size_t)z * NROWS * CDIM + base);
        o0 += bf2f(p.x) * e[z];
        o1 += bf2f(p.y) * e[z];
        o2 += bf2f(p.z) * e[z];
        o3 += bf2f(p.w) * e[z];
    }
    ushort4 o;
    o.x = f2bf(o0 * rden); o.y = f2bf(o1 * rden);
    o.z = f2bf(o2 * rden); o.w = f2bf(o3 * rden);
    *(ushort4*)(out + base) = o;
}

// ---------------------------------------------------------------- launch
extern "C" void kernel_launch(void* const* d_in, const int* in_sizes, int n_in,
                              void* d_out, int out_size, void* d_ws, size_t ws_size,
                              hipStream_t stream) {
    const float* x     = (const float*)d_in[0];
    const float* ctx   = (const float*)d_in[1];
    const float* ln1g  = (const float*)d_in[2];
    const float* ln1b  = (const float*)d_in[3];
    const float* ln2g  = (const float*)d_in[4];
    const float* ln2b  = (const float*)d_in[5];
    const float* ln3g  = (const float*)d_in[6];
    const float* ln3b  = (const float*)d_in[7];
    const float* sa_wq = (const float*)d_in[8];
    const float* sa_bq = (const float*)d_in[9];
    const float* sa_wk = (const float*)d_in[10];
    const float* sa_bk = (const float*)d_in[11];
    const float* sa_wv = (const float*)d_in[12];
    const float* sa_bv = (const float*)d_in[13];
    const float* sa_wo = (const float*)d_in[14];
    const float* sa_bo = (const float*)d_in[15];
    const float* xa_wq = (const float*)d_in[16];
    const float* xa_bq = (const float*)d_in[17];
    const float* xa_wk = (const float*)d_in[18];
    const float* xa_bk = (const float*)d_in[19];
    const float* xa_wv = (const float*)d_in[20];
    const float* xa_bv = (const float*)d_in[21];
    const float* xa_wo = (const float*)d_in[22];
    const float* xa_bo = (const float*)d_in[23];
    const float* m_w1  = (const float*)d_in[24];
    const float* m_b1  = (const float*)d_in[25];
    const float* m_w2  = (const float*)d_in[26];
    const float* m_b2  = (const float*)d_in[27];

    float* out_x   = (float*)d_out;
    float* out_ctx = out_x + (size_t)NROWS * CDIM;
    // d_out doubles as scratch: bf16 split-KV partials during attention,
    // then m_w2^T (4.7MB, in the out_ctx half) during the MLP. The ctx
    // passthrough memcpy is the LAST op.
    u16* Opart = (u16*)d_out;
    u16* W2s   = (u16*)out_ctx;

    const size_t SZ_ACT  = (size_t)NROWS * CDIM * 2;
    const size_t SZ_WBIG = (size_t)HDIM * CDIM * 2;
    const size_t SZ_R    = (size_t)NROWS * CDIM * 4;
    const size_t NEEDED  = 5 * SZ_ACT + SZ_R + SZ_WBIG;
    if (ws_size < NEEDED) return;

    char* ws = (char*)d_ws;
    u16* qb    = (u16*)(ws);
    u16* kb    = (u16*)(ws + 1 * SZ_ACT);
    u16* vb    = (u16*)(ws + 2 * SZ_ACT);
    u16* ctxb  = (u16*)(ws + 3 * SZ_ACT);
    u16* hb    = qb;
    u16* lnbuf = (u16*)(ws + 4 * SZ_ACT);
    u16* attB  = lnbuf;
    float* R   = (float*)(ws + 5 * SZ_ACT);
    u16* Wq    = (u16*)(ws + 5 * SZ_ACT + SZ_R);   // pool: [Wq][Wk][Wv][Wo]
    u16* Wk    = Wq + (size_t)CDIM * CDIM;
    u16* Wv    = Wk + (size_t)CDIM * CDIM;
    u16* Wo    = Wv + (size_t)CDIM * CDIM;
    // ml (1.57MB) overlays Wq+Wk (dead after the QKV GEMM); Wo survives.
    float2* ml = (float2*)Wq;

    const dim3 tb(256);
    GemmArgs ga;

    // ---- self-attention
    Pre1 p1;
    p1.ctx = ctx; p1.ctxb = ctxb;
    p1.x = x; p1.g = ln1g; p1.bta = ln1b; p1.lnout = lnbuf;
    p1.w[0] = sa_wq; p1.w[1] = sa_wk; p1.w[2] = sa_wv; p1.w[3] = sa_wo;
    p1.wt[0] = Wq;   p1.wt[1] = Wk;   p1.wt[2] = Wv;   p1.wt[3] = Wo;
    pre1_kernel<<<dim3(3072 + 4096 + 2304), tb, 0, stream>>>(p1);
    ga = GemmArgs{};
    ga.A[0] = lnbuf; ga.BT[0] = Wq; ga.bias[0] = sa_bq; ga.out[0] = qb; ga.alpha[0] = QSCALE;
    ga.A[1] = lnbuf; ga.BT[1] = Wk; ga.bias[1] = sa_bk; ga.out[1] = kb; ga.alpha[1] = 1.f;
    ga.A[2] = lnbuf; ga.BT[2] = Wv; ga.bias[2] = sa_bv; ga.out[2] = vb; ga.alpha[2] = 1.f;
    ga.M = 4096; ga.N = 768; ga.K = 768;
    gemm_bt<0, 128, 64><<<dim3(32, 12, 3), tb, 0, stream>>>(ga);
    attn_split<<<dim3(16, 24, KVSPLIT), tb, 0, stream>>>(qb, kb, vb, Opart, ml);
    attn_merge4<<<dim3(NROWS * CDIM / 1024), tb, 0, stream>>>(Opart, ml, attB);
    ga = GemmArgs{};
    ga.A[0] = attB; ga.BT[0] = Wo; ga.bias[0] = sa_bo; ga.res[0] = x; ga.out[0] = R; ga.alpha[0] = 1.f;
    ga.M = 4096; ga.N = 768; ga.K = 768;
    gemm_bt<1, 64, 64><<<dim3(64, 12, 1), tb, 0, stream>>>(ga);

    // ---- cross-attention
    Pre2 p2;
    p2.x = R; p2.g = ln2g; p2.bta = ln2b; p2.lnout = lnbuf;
    p2.w[0] = xa_wq; p2.w[1] = xa_wk; p2.w[2] = xa_wv; p2.w[3] = xa_wo;
    p2.wt[0] = Wq;   p2.wt[1] = Wk;   p2.wt[2] = Wv;   p2.wt[3] = Wo;
    pre2_kernel<<<dim3(4096 + 2304), tb, 0, stream>>>(p2);
    ga = GemmArgs{};
    ga.A[0] = lnbuf; ga.BT[0] = Wq; ga.bias[0] = xa_bq; ga.out[0] = qb; ga.alpha[0] = QSCALE;
    ga.A[1] = ctxb;  ga.BT[1] = Wk; ga.bias[1] = xa_bk; ga.out[1] = kb; ga.alpha[1] = 1.f;
    ga.A[2] = ctxb;  ga.BT[2] = Wv; ga.bias[2] = xa_bv; ga.out[2] = vb; ga.alpha[2] = 1.f;
    ga.M = 4096; ga.N = 768; ga.K = 768;
    gemm_bt<0, 128, 64><<<dim3(32, 12, 3), tb, 0, stream>>>(ga);
    attn_split<<<dim3(16, 24, KVSPLIT), tb, 0, stream>>>(qb, kb, vb, Opart, ml);
    attn_merge4<<<dim3(NROWS * CDIM / 1024), tb, 0, stream>>>(Opart, ml, attB);
    ga = GemmArgs{};
    ga.A[0] = attB; ga.BT[0] = Wo; ga.bias[0] = xa_bo; ga.res[0] = R; ga.out[0] = R; ga.alpha[0] = 1.f;
    ga.M = 4096; ga.N = 768; ga.K = 768;
    gemm_bt<1, 64, 64><<<dim3(64, 12, 1), tb, 0, stream>>>(ga);

    // ---- MLP (m_w2^T staged in the dead out_ctx half of d_out)
    Pre3 p3;
    p3.x = R; p3.g = ln3g; p3.bta = ln3b; p3.lnout = lnbuf;
    p3.w1 = m_w1; p3.wt1 = Wq;
    p3.w2 = m_w2; p3.wt2 = W2s;
    pre3_kernel<<<dim3(4096 + 2304 + 2304), tb, 0, stream>>>(p3);
    ga = GemmArgs{};
    ga.A[0] = lnbuf; ga.BT[0] = Wq; ga.bias[0] = m_b1; ga.out[0] = hb; ga.alpha[0] = 1.f;
    ga.M = 4096; ga.N = 3072; ga.K = 768;
    gemm_bt<2, 128, 64><<<dim3(32, 48, 1), tb, 0, stream>>>(ga);
    ga = GemmArgs{};
    ga.A[0] = hb; ga.BT[0] = W2s; ga.bias[0] = m_b2; ga.res[0] = R; ga.out[0] = out_x; ga.alpha[0] = 1.f;
    ga.M = 4096; ga.N = 768; ga.K = 3072;
    gemm_bt<1, 64, 64><<<dim3(64, 12, 1), tb, 0, stream>>>(ga);
    // context passthrough LAST (d_out scratch roles all expired)
    hipMemcpyAsync(out_ctx, ctx, (size_t)NROWS * CDIM * 4,
                   hipMemcpyDeviceToDevice, stream);

    (void)in_sizes; (void)n_in; (void)out_size;
}

// Round 17
// 319.781 us; speedup vs baseline: 1.0825x; 1.0825x over previous
//
#include <hip/hip_runtime.h>
#include <hip/hip_bf16.h>
#include <math.h>

#define CDIM 768
#define HDIM 3072
#define NROWS 4096   // B*T
#define TSEQ 2048
#define NHEAD 12
#define KVSPLIT 4
#define KVLEN (TSEQ / KVSPLIT)   // 512 rows per part

typedef unsigned short u16;
typedef unsigned int   u32;
typedef __attribute__((ext_vector_type(8))) short short8;
typedef __attribute__((ext_vector_type(4))) float f32x4;

// 1/sqrt(64) * log2(e): folds the softmax ln->log2 conversion into Q
#define QSCALE 0.18033688011112042f

static __device__ __forceinline__ u16 f2bf(float f) {
    u32 x = __float_as_uint(f);
    x += 0x7fffu + ((x >> 16) & 1u);
    return (u16)(x >> 16);
}
static __device__ __forceinline__ float bf2f(u16 x) {
    return __uint_as_float((u32)x << 16);
}
static __device__ __forceinline__ u32 cvt_pk_bf16(float lo, float hi) {
    u32 r;
    asm("v_cvt_pk_bf16_f32 %0, %1, %2" : "=v"(r) : "v"(lo), "v"(hi));
    return r;
}

#define GLL16(g, l)                                                            \
    __builtin_amdgcn_global_load_lds(                                          \
        (const __attribute__((address_space(1))) void*)(g),                    \
        (__attribute__((address_space(3))) void*)(l), 16, 0, 0)

// ---------------------------------------------------------------- packed pre-work helpers
static __device__ void do_cvt(int blk, const float* __restrict__ in,
                              u16* __restrict__ out) {
    const int i = blk * 256 + threadIdx.x;   // float4 index, exact multiple
    float4 v = ((const float4*)in)[i];
    ushort4 o;
    o.x = f2bf(v.x); o.y = f2bf(v.y); o.z = f2bf(v.z); o.w = f2bf(v.w);
    ((ushort4*)out)[i] = o;
}

static __device__ void do_ln(int row, const float* __restrict__ x,
                             const float* __restrict__ g,
                             const float* __restrict__ bta,
                             u16* __restrict__ out, float* red) {
    const int tid = threadIdx.x;
    const float* xr = x + (size_t)row * CDIM;
    float v0 = xr[tid], v1 = xr[tid + 256], v2 = xr[tid + 512];
    float s = v0 + v1 + v2;
#pragma unroll
    for (int m = 1; m < 64; m <<= 1) s += __shfl_xor(s, m);
    if ((tid & 63) == 0) red[tid >> 6] = s;
    __syncthreads();
    const float mu = (red[0] + red[1] + red[2] + red[3]) * (1.f / CDIM);
    const float d0 = v0 - mu, d1 = v1 - mu, d2 = v2 - mu;
    float q = d0 * d0 + d1 * d1 + d2 * d2;
#pragma unroll
    for (int m = 1; m < 64; m <<= 1) q += __shfl_xor(q, m);
    if ((tid & 63) == 0) red[4 + (tid >> 6)] = q;
    __syncthreads();
    const float var = (red[4] + red[5] + red[6] + red[7]) * (1.f / CDIM);
    const float rstd = rsqrtf(var + 1e-5f);
    u16* orow = out + (size_t)row * CDIM;
    orow[tid]       = f2bf(d0 * rstd * g[tid]       + bta[tid]);
    orow[tid + 256] = f2bf(d1 * rstd * g[tid + 256] + bta[tid + 256]);
    orow[tid + 512] = f2bf(d2 * rstd * g[tid + 512] + bta[tid + 512]);
}

static __device__ void do_wt(int bx, int by, const float* __restrict__ w,
                             u16* __restrict__ wt, int K, int N, float* t /*32x33*/) {
    const int n0 = bx * 32, k0 = by * 32;
    const int tx = threadIdx.x & 31, ty = threadIdx.x >> 5;
#pragma unroll
    for (int i = ty; i < 32; i += 8)
        t[i * 33 + tx] = w[(size_t)(k0 + i) * N + n0 + tx];
    __syncthreads();
#pragma unroll
    for (int i = ty; i < 32; i += 8)
        wt[(size_t)(n0 + i) * K + k0 + tx] = f2bf(t[tx * 33 + i]);
}

// pre1: cvt_copy (3072) | LN1 (4096) | SA wtrans x4 (2304)
struct Pre1 {
    const float* ctx; u16* ctxb;
    const float* x; const float* g; const float* bta; u16* lnout;
    const float* w[4]; u16* wt[4];
};
__launch_bounds__(256)
__global__ void pre1_kernel(Pre1 p) {
    __shared__ float smem[32 * 33];
    int bid = blockIdx.x;
    if (bid < 3072) { do_cvt(bid, p.ctx, p.ctxb); return; }
    bid -= 3072;
    if (bid < 4096) { do_ln(bid, p.x, p.g, p.bta, p.lnout, smem); return; }
    bid -= 4096;
    const int z = bid / 576, rem = bid % 576;
    do_wt(rem % 24, rem / 24, p.w[z], p.wt[z], CDIM, CDIM, smem);
}

// pre2: LN (4096) | wtrans x4 (2304)
struct Pre2 {
    const float* x; const float* g; const float* bta; u16* lnout;
    const float* w[4]; u16* wt[4];
};
__launch_bounds__(256)
__global__ void pre2_kernel(Pre2 p) {
    __shared__ float smem[32 * 33];
    int bid = blockIdx.x;
    if (bid < 4096) { do_ln(bid, p.x, p.g, p.bta, p.lnout, smem); return; }
    bid -= 4096;
    const int z = bid / 576, rem = bid % 576;
    do_wt(rem % 24, rem / 24, p.w[z], p.wt[z], CDIM, CDIM, smem);
}

// pre3: LN3 (4096) | m_w1^T (2304: 96x24) | m_w2^T (2304: 24x96)
struct Pre3 {
    const float* x; const float* g; const float* bta; u16* lnout;
    const float* w1; u16* wt1;
    const float* w2; u16* wt2;
};
__launch_bounds__(256)
__global__ void pre3_kernel(Pre3 p) {
    __shared__ float smem[32 * 33];
    int bid = blockIdx.x;
    if (bid < 4096) { do_ln(bid, p.x, p.g, p.bta, p.lnout, smem); return; }
    bid -= 4096;
    if (bid < 2304) { do_wt(bid % 96, bid / 96, p.w1, p.wt1, CDIM, HDIM, smem); return; }
    bid -= 2304;
    do_wt(bid % 24, bid / 24, p.w2, p.wt2, HDIM, CDIM, smem);
}

// ---------------------------------------------------------------- GEMM (R12-verified)
struct GemmArgs {
    const u16* A[3];
    const u16* BT[3];
    const float* bias[3];
    const float* res[3];
    void* out[3];
    float alpha[3];
    int M, N, K;
};

// EPI: 0 = (s+bias)*alpha -> bf16 ; 1 = res + s + bias -> f32 ; 2 = gelu -> bf16
// launch_bounds(256,4): cap VGPR at 128 so >=4 blocks/CU stay resident (m114
// wave-overlap hides the vmcnt(0)+barrier drain). Audit: worst case ~100 VGPR.
template <int EPI, int BM, int BN = 128>
__launch_bounds__(256, 4)
__global__ void gemm_bt(GemmArgs ga) {
    constexpr int MF = BM / 32, NF = BN / 32;
    __shared__ u16 Abuf[BM * 32];
    __shared__ u16 Bbuf[BN * 32];
    const int z = blockIdx.z;
    const u16* __restrict__ A  = ga.A[z];
    const u16* __restrict__ BT = ga.BT[z];
    const float* __restrict__ bias = ga.bias[z];
    const float* __restrict__ res  = ga.res[z];
    void* outv = ga.out[z];
    const float alpha = ga.alpha[z];
    const int N = ga.N, K = ga.K;

    const int tid = threadIdx.x;
    const int lane = tid & 63, w = tid >> 6;
    const int m0 = blockIdx.x * BM, n0 = blockIdx.y * BN;
    const int wr = (w >> 1) * (BM / 2), wc = (w & 1) * (BN / 2);
    const int lr = lane & 15, lc = lane >> 4;

    const int srowA = (BM == 128) ? (w * 32 + (lane >> 2)) : (tid >> 2);
    const int srowB = (BN == 128) ? (w * 32 + (lane >> 2)) : (tid >> 2);
    const int scol = (lane & 3) * 8;
    const u16* Ag = A + (size_t)(m0 + srowA) * K + scol;
    const u16* Bg = BT + (size_t)(n0 + srowB) * K + scol;
    char* Ab = (char*)Abuf + w * (BM == 128 ? 2048 : 1024);
    char* Bb = (char*)Bbuf + w * (BN == 128 ? 2048 : 1024);

    f32x4 acc[MF][NF];
#pragma unroll
    for (int m = 0; m < MF; ++m)
#pragma unroll
        for (int n = 0; n < NF; ++n) acc[m][n] = (f32x4){0.f, 0.f, 0.f, 0.f};

    const int nk = K >> 5;
    for (int kt = 0; kt < nk; ++kt) {
        const int ko = kt * 32;
        GLL16(Ag + ko, Ab);
        if constexpr (BM == 128) GLL16(Ag + 16 * K + ko, Ab + 1024);
        GLL16(Bg + ko, Bb);
        if constexpr (BN == 128) GLL16(Bg + 16 * K + ko, Bb + 1024);
        __syncthreads();
        short8 af[MF], bfv[NF];
#pragma unroll
        for (int m = 0; m < MF; ++m)
            af[m] = *(const short8*)((const char*)Abuf +
                                     (size_t)(wr + m * 16 + lr) * 64 + lc * 16);
#pragma unroll
        for (int n = 0; n < NF; ++n)
            bfv[n] = *(const short8*)((const char*)Bbuf +
                                      (size_t)(wc + n * 16 + lr) * 64 + lc * 16);
#pragma unroll
        for (int m = 0; m < MF; ++m)
#pragma unroll
            for (int n = 0; n < NF; ++n)
                acc[m][n] = __builtin_amdgcn_mfma_f32_16x16x32_bf16(
                    af[m], bfv[n], acc[m][n], 0, 0, 0);
        __syncthreads();
    }

#pragma unroll
    for (int n = 0; n < NF; ++n) {
        const int gc = n0 + wc + n * 16 + lr;
        const float bs = bias[gc];
#pragma unroll
        for (int m = 0; m < MF; ++m) {
            const int gr = m0 + wr + m * 16 + lc * 4;
#pragma unroll
            for (int r = 0; r < 4; ++r) {
                float v = (acc[m][n][r] + bs) * alpha;
                const size_t idx = (size_t)(gr + r) * N + gc;
                if constexpr (EPI == 0) {
                    ((u16*)outv)[idx] = f2bf(v);
                } else if constexpr (EPI == 1) {
                    ((float*)outv)[idx] = res[idx] + v;
                } else {
                    float gel = 0.5f * v * (1.0f + erff(v * 0.70710678118654752f));
                    ((u16*)outv)[idx] = f2bf(gel);
                }
            }
        }
    }
}

// ---------------------------------------------------------------- attention helpers
static __device__ __forceinline__ void softmax_pack(f32x4 sf[4], float& mrow,
                                                    float& lrow, f32x4 oacc[4],
                                                    short8& p0, short8& p1) {
    float pm;
    {
        float a0 = fmaxf(fmaxf(sf[0][0], sf[0][1]), fmaxf(sf[0][2], sf[0][3]));
        float a1 = fmaxf(fmaxf(sf[1][0], sf[1][1]), fmaxf(sf[1][2], sf[1][3]));
        float a2 = fmaxf(fmaxf(sf[2][0], sf[2][1]), fmaxf(sf[2][2], sf[2][3]));
        float a3 = fmaxf(fmaxf(sf[3][0], sf[3][1]), fmaxf(sf[3][2], sf[3][3]));
        pm = fmaxf(fmaxf(a0, a1), fmaxf(a2, a3));
        pm = fmaxf(pm, __shfl_xor(pm, 16));
        pm = fmaxf(pm, __shfl_xor(pm, 32));
    }
    // defer-max: only rescale when some q-row's max grew (wave-uniform)
    if (!__all(pm <= mrow)) {
        const float mn = fmaxf(mrow, pm);
        const float corr = exp2f(mrow - mn);
        mrow = mn;
        lrow *= corr;
#pragma unroll
        for (int fd = 0; fd < 4; ++fd)
#pragma unroll
            for (int r = 0; r < 4; ++r) oacc[fd][r] *= corr;
    }
#pragma unroll
    for (int fn = 0; fn < 4; ++fn)
#pragma unroll
        for (int r = 0; r < 4; ++r) sf[fn][r] = exp2f(sf[fn][r] - mrow);
    float rs;
    {
        float s0 = (sf[0][0] + sf[0][1]) + (sf[0][2] + sf[0][3]);
        float s1 = (sf[1][0] + sf[1][1]) + (sf[1][2] + sf[1][3]);
        float s2 = (sf[2][0] + sf[2][1]) + (sf[2][2] + sf[2][3]);
        float s3 = (sf[3][0] + sf[3][1]) + (sf[3][2] + sf[3][3]);
        rs = (s0 + s1) + (s2 + s3);
        rs += __shfl_xor(rs, 16);
        rs += __shfl_xor(rs, 32);
    }
    lrow += rs;
    int4 pw0, pw1;
    pw0.x = cvt_pk_bf16(sf[0][0], sf[0][1]);
    pw0.y = cvt_pk_bf16(sf[0][2], sf[0][3]);
    pw0.z = cvt_pk_bf16(sf[1][0], sf[1][1]);
    pw0.w = cvt_pk_bf16(sf[1][2], sf[1][3]);
    pw1.x = cvt_pk_bf16(sf[2][0], sf[2][1]);
    pw1.y = cvt_pk_bf16(sf[2][2], sf[2][3]);
    pw1.z = cvt_pk_bf16(sf[3][0], sf[3][1]);
    pw1.w = cvt_pk_bf16(sf[3][2], sf[3][3]);
    p0 = *(short8*)&pw0;
    p1 = *(short8*)&pw1;
}

// ---------------------------------------------------------------- attention (split-KV, 128q/block)
__launch_bounds__(256, 4)
__global__ void attn_split(const u16* __restrict__ Qb, const u16* __restrict__ Kb,
                           const u16* __restrict__ Vb, u16* __restrict__ Opart,
                           float2* __restrict__ ml) {
    __shared__ u16 Klds[64 * 72];
    __shared__ u16 Vt[64 * 72];
    const int tid = threadIdx.x;
    const int lane = tid & 63, w = tid >> 6;
    const int lr = lane & 15, lc = lane >> 4;
    const int b = blockIdx.y / NHEAD, h = blockIdx.y % NHEAD;
    const int z = blockIdx.z;
    const size_t qrowA = (size_t)b * TSEQ + blockIdx.x * 128 + w * 16;
    const size_t qrowB = qrowA + 64;
    const size_t krow0 = (size_t)b * TSEQ + (size_t)z * KVLEN;
    const int hc = h * 64;

    short8 qa0, qa1, qb0, qb1;
    {
        const u16* qp = Qb + (qrowA + lr) * CDIM + hc + lc * 8;
        qa0 = *(const short8*)qp;
        qa1 = *(const short8*)(qp + 32);
        const u16* qp2 = Qb + (qrowB + lr) * CDIM + hc + lc * 8;
        qb0 = *(const short8*)qp2;
        qb1 = *(const short8*)(qp2 + 32);
    }
    f32x4 oaccA[4], oaccB[4];
#pragma unroll
    for (int r = 0; r < 4; ++r) {
        oaccA[r] = (f32x4){0.f, 0.f, 0.f, 0.f};
        oaccB[r] = (f32x4){0.f, 0.f, 0.f, 0.f};
    }
    float mA = -3e38f, lA = 0.f, mB = -3e38f, lB = 0.f;

    const int stg_r = tid >> 2, stg_s = tid & 3;
    const u16* kg = Kb + (krow0 + stg_r) * CDIM + hc + stg_s * 16;
    const u16* vg = Vb + (krow0 + stg_r) * CDIM + hc + stg_s * 16;
    uint4 ka0 = *(const uint4*)kg, ka1 = *(const uint4*)(kg + 8);
    uint4 va0 = *(const uint4*)vg, va1 = *(const uint4*)(vg + 8);
    const int sig = ((stg_r >> 5) << 5) + (((stg_r >> 2) & 3) << 3) +
                    (((stg_r >> 4) & 1) << 2) + (stg_r & 3);
    char* vdst = (char*)Vt + ((2 * sig) ^ (stg_s << 5)) +
                 (size_t)(stg_s * 16) * 144;

    for (int kt = 0; kt < KVLEN / 64; ++kt) {
        __syncthreads();
        {
            *(uint4*)&Klds[stg_r * 72 + stg_s * 16]     = ka0;
            *(uint4*)&Klds[stg_r * 72 + stg_s * 16 + 8] = ka1;
            u16 tmp[16];
            *(uint4*)(tmp)     = va0;
            *(uint4*)(tmp + 8) = va1;
#pragma unroll
            for (int j = 0; j < 16; ++j)
                *(u16*)(vdst + (size_t)j * 144) = tmp[j];
        }
        if (kt < KVLEN / 64 - 1) {
            kg += 64 * CDIM; vg += 64 * CDIM;
            ka0 = *(const uint4*)kg; ka1 = *(const uint4*)(kg + 8);
            va0 = *(const uint4*)vg; va1 = *(const uint4*)(vg + 8);
        }
        __syncthreads();

        // S^T = K * Q^T for both q-groups; each K fragment read used twice
        f32x4 sfA[4], sfB[4];
#pragma unroll
        for (int fn = 0; fn < 4; ++fn) {
            const u16* kr = &Klds[(lr + fn * 16) * 72 + lc * 8];
            short8 kb0 = *(const short8*)kr;
            short8 kb1 = *(const short8*)(kr + 32);
            f32x4 t = (f32x4){0.f, 0.f, 0.f, 0.f};
            t = __builtin_amdgcn_mfma_f32_16x16x32_bf16(kb0, qa0, t, 0, 0, 0);
            t = __builtin_amdgcn_mfma_f32_16x16x32_bf16(kb1, qa1, t, 0, 0, 0);
            sfA[fn] = t;
            f32x4 u = (f32x4){0.f, 0.f, 0.f, 0.f};
            u = __builtin_amdgcn_mfma_f32_16x16x32_bf16(kb0, qb0, u, 0, 0, 0);
            u = __builtin_amdgcn_mfma_f32_16x16x32_bf16(kb1, qb1, u, 0, 0, 0);
            sfB[fn] = u;
        }

        short8 pA0, pA1, pB0, pB1;
        softmax_pack(sfA, mA, lA, oaccA, pA0, pA1);
        softmax_pack(sfB, mB, lB, oaccB, pB0, pB1);

        // O^T += V^T * P^T ; each V fragment read used twice
#pragma unroll
        for (int fd = 0; fd < 4; ++fd) {
            const char* vtb = (const char*)Vt + (size_t)(lr + fd * 16) * 144;
            short8 vb0 = *(const short8*)(vtb + ((lc * 16) ^ (fd * 32)));
            short8 vb1 = *(const short8*)(vtb + ((lc * 16 + 64) ^ (fd * 32)));
            oaccA[fd] = __builtin_amdgcn_mfma_f32_16x16x32_bf16(vb0, pA0, oaccA[fd], 0, 0, 0);
            oaccA[fd] = __builtin_amdgcn_mfma_f32_16x16x32_bf16(vb1, pA1, oaccA[fd], 0, 0, 0);
            oaccB[fd] = __builtin_amdgcn_mfma_f32_16x16x32_bf16(vb0, pB0, oaccB[fd], 0, 0, 0);
            oaccB[fd] = __builtin_amdgcn_mfma_f32_16x16x32_bf16(vb1, pB1, oaccB[fd], 0, 0, 0);
        }
    }

    // epilogue: UNNORMALIZED bf16 partials + (m,l) for both groups
    u16* oA = Opart + (size_t)z * NROWS * CDIM + (qrowA + lr) * CDIM + hc + lc * 4;
    u16* oB = Opart + (size_t)z * NROWS * CDIM + (qrowB + lr) * CDIM + hc + lc * 4;
#pragma unroll
    for (int fd = 0; fd < 4; ++fd) {
        ushort4 o;
        o.x = f2bf(oaccA[fd][0]); o.y = f2bf(oaccA[fd][1]);
        o.z = f2bf(oaccA[fd][2]); o.w = f2bf(oaccA[fd][3]);
        *(ushort4*)(oA + fd * 16) = o;
        o.x = f2bf(oaccB[fd][0]); o.y = f2bf(oaccB[fd][1]);
        o.z = f2bf(oaccB[fd][2]); o.w = f2bf(oaccB[fd][3]);
        *(ushort4*)(oB + fd * 16) = o;
    }
    if (lc == 0) {
        ml[((size_t)z * NROWS + qrowA + lr) * NHEAD + h] = (float2){mA, lA};
        ml[((size_t)z * NROWS + qrowB + lr) * NHEAD + h] = (float2){mB, lB};
    }
}

// ---------------------------------------------------------------- merge (4 parts)
__launch_bounds__(256)
__global__ void attn_merge4(const u16* __restrict__ P, const float2* __restrict__ ml,
                            u16* __restrict__ out) {
    const int i4 = blockIdx.x * 256 + threadIdx.x;   // 4-elem chunk index
    const size_t base = (size_t)i4 * 4;
    const int row = (int)(base / CDIM);
    const int head = (int)(base - (size_t)row * CDIM) >> 6;
    float2 a[KVSPLIT];
    float M = -3e38f;
#pragma unroll
    for (int z = 0; z < KVSPLIT; ++z) {
        a[z] = ml[((size_t)z * NROWS + row) * NHEAD + head];
        M = fmaxf(M, a[z].x);
    }
    float den = 0.f, e[KVSPLIT];
#pragma unroll
    for (int z = 0; z < KVSPLIT; ++z) {
        e[z] = exp2f(a[z].x - M);
        den += a[z].y * e[z];
    }
    const float rden = 1.f / den;
    float o0 = 0.f, o1 = 0.f, o2 = 0.f, o3 = 0.f;
#pragma unroll
    for (int z = 0; z < KVSPLIT; ++z) {
        ushort4 p = *(const ushort4*)(P + (size_t)z * NROWS * CDIM + base);
        o0 += bf2f(p.x) * e[z];
        o1 += bf2f(p.y) * e[z];
        o2 += bf2f(p.z) * e[z];
        o3 += bf2f(p.w) * e[z];
    }
    ushort4 o;
    o.x = f2bf(o0 * rden); o.y = f2bf(o1 * rden);
    o.z = f2bf(o2 * rden); o.w = f2bf(o3 * rden);
    *(ushort4*)(out + base) = o;
}

// ---------------------------------------------------------------- launch
extern "C" void kernel_launch(void* const* d_in, const int* in_sizes, int n_in,
                              void* d_out, int out_size, void* d_ws, size_t ws_size,
                              hipStream_t stream) {
    const float* x     = (const float*)d_in[0];
    const float* ctx   = (const float*)d_in[1];
    const float* ln1g  = (const float*)d_in[2];
    const float* ln1b  = (const float*)d_in[3];
    const float* ln2g  = (const float*)d_in[4];
    const float* ln2b  = (const float*)d_in[5];
    const float* ln3g  = (const float*)d_in[6];
    const float* ln3b  = (const float*)d_in[7];
    const float* sa_wq = (const float*)d_in[8];
    const float* sa_bq = (const float*)d_in[9];
    const float* sa_wk = (const float*)d_in[10];
    const float* sa_bk = (const float*)d_in[11];
    const float* sa_wv = (const float*)d_in[12];
    const float* sa_bv = (const float*)d_in[13];
    const float* sa_wo = (const float*)d_in[14];
    const float* sa_bo = (const float*)d_in[15];
    const float* xa_wq = (const float*)d_in[16];
    const float* xa_bq = (const float*)d_in[17];
    const float* xa_wk = (const float*)d_in[18];
    const float* xa_bk = (const float*)d_in[19];
    const float* xa_wv = (const float*)d_in[20];
    const float* xa_bv = (const float*)d_in[21];
    const float* xa_wo = (const float*)d_in[22];
    const float* xa_bo = (const float*)d_in[23];
    const float* m_w1  = (const float*)d_in[24];
    const float* m_b1  = (const float*)d_in[25];
    const float* m_w2  = (const float*)d_in[26];
    const float* m_b2  = (const float*)d_in[27];

    float* out_x   = (float*)d_out;
    float* out_ctx = out_x + (size_t)NROWS * CDIM;
    // d_out doubles as scratch: bf16 split-KV partials during attention,
    // then m_w2^T (4.7MB, in the out_ctx half) during the MLP. The ctx
    // passthrough memcpy is the LAST op.
    u16* Opart = (u16*)d_out;
    u16* W2s   = (u16*)out_ctx;

    const size_t SZ_ACT  = (size_t)NROWS * CDIM * 2;
    const size_t SZ_WBIG = (size_t)HDIM * CDIM * 2;
    const size_t SZ_R    = (size_t)NROWS * CDIM * 4;
    const size_t NEEDED  = 5 * SZ_ACT + SZ_R + SZ_WBIG;
    if (ws_size < NEEDED) return;

    char* ws = (char*)d_ws;
    u16* qb    = (u16*)(ws);
    u16* kb    = (u16*)(ws + 1 * SZ_ACT);
    u16* vb    = (u16*)(ws + 2 * SZ_ACT);
    u16* ctxb  = (u16*)(ws + 3 * SZ_ACT);
    u16* hb    = qb;
    u16* lnbuf = (u16*)(ws + 4 * SZ_ACT);
    u16* attB  = lnbuf;
    float* R   = (float*)(ws + 5 * SZ_ACT);
    u16* Wq    = (u16*)(ws + 5 * SZ_ACT + SZ_R);   // pool: [Wq][Wk][Wv][Wo]
    u16* Wk    = Wq + (size_t)CDIM * CDIM;
    u16* Wv    = Wk + (size_t)CDIM * CDIM;
    u16* Wo    = Wv + (size_t)CDIM * CDIM;
    // ml (1.57MB) overlays Wq+Wk (dead after the QKV GEMM); Wo survives.
    float2* ml = (float2*)Wq;

    const dim3 tb(256);
    GemmArgs ga;

    // ---- self-attention
    Pre1 p1;
    p1.ctx = ctx; p1.ctxb = ctxb;
    p1.x = x; p1.g = ln1g; p1.bta = ln1b; p1.lnout = lnbuf;
    p1.w[0] = sa_wq; p1.w[1] = sa_wk; p1.w[2] = sa_wv; p1.w[3] = sa_wo;
    p1.wt[0] = Wq;   p1.wt[1] = Wk;   p1.wt[2] = Wv;   p1.wt[3] = Wo;
    pre1_kernel<<<dim3(3072 + 4096 + 2304), tb, 0, stream>>>(p1);
    ga = GemmArgs{};
    ga.A[0] = lnbuf; ga.BT[0] = Wq; ga.bias[0] = sa_bq; ga.out[0] = qb; ga.alpha[0] = QSCALE;
    ga.A[1] = lnbuf; ga.BT[1] = Wk; ga.bias[1] = sa_bk; ga.out[1] = kb; ga.alpha[1] = 1.f;
    ga.A[2] = lnbuf; ga.BT[2] = Wv; ga.bias[2] = sa_bv; ga.out[2] = vb; ga.alpha[2] = 1.f;
    ga.M = 4096; ga.N = 768; ga.K = 768;
    gemm_bt<0, 128, 64><<<dim3(32, 12, 3), tb, 0, stream>>>(ga);
    attn_split<<<dim3(16, 24, KVSPLIT), tb, 0, stream>>>(qb, kb, vb, Opart, ml);
    attn_merge4<<<dim3(NROWS * CDIM / 1024), tb, 0, stream>>>(Opart, ml, attB);
    ga = GemmArgs{};
    ga.A[0] = attB; ga.BT[0] = Wo; ga.bias[0] = sa_bo; ga.res[0] = x; ga.out[0] = R; ga.alpha[0] = 1.f;
    ga.M = 4096; ga.N = 768; ga.K = 768;
    gemm_bt<1, 64, 64><<<dim3(64, 12, 1), tb, 0, stream>>>(ga);

    // ---- cross-attention
    Pre2 p2;
    p2.x = R; p2.g = ln2g; p2.bta = ln2b; p2.lnout = lnbuf;
    p2.w[0] = xa_wq; p2.w[1] = xa_wk; p2.w[2] = xa_wv; p2.w[3] = xa_wo;
    p2.wt[0] = Wq;   p2.wt[1] = Wk;   p2.wt[2] = Wv;   p2.wt[3] = Wo;
    pre2_kernel<<<dim3(4096 + 2304), tb, 0, stream>>>(p2);
    ga = GemmArgs{};
    ga.A[0] = lnbuf; ga.BT[0] = Wq; ga.bias[0] = xa_bq; ga.out[0] = qb; ga.alpha[0] = QSCALE;
    ga.A[1] = ctxb;  ga.BT[1] = Wk; ga.bias[1] = xa_bk; ga.out[1] = kb; ga.alpha[1] = 1.f;
    ga.A[2] = ctxb;  ga.BT[2] = Wv; ga.bias[2] = xa_bv; ga.out[2] = vb; ga.alpha[2] = 1.f;
    ga.M = 4096; ga.N = 768; ga.K = 768;
    gemm_bt<0, 128, 64><<<dim3(32, 12, 3), tb, 0, stream>>>(ga);
    attn_split<<<dim3(16, 24, KVSPLIT), tb, 0, stream>>>(qb, kb, vb, Opart, ml);
    attn_merge4<<<dim3(NROWS * CDIM / 1024), tb, 0, stream>>>(Opart, ml, attB);
    ga = GemmArgs{};
    ga.A[0] = attB; ga.BT[0] = Wo; ga.bias[0] = xa_bo; ga.res[0] = R; ga.out[0] = R; ga.alpha[0] = 1.f;
    ga.M = 4096; ga.N = 768; ga.K = 768;
    gemm_bt<1, 64, 64><<<dim3(64, 12, 1), tb, 0, stream>>>(ga);

    // ---- MLP (m_w2^T staged in the dead out_ctx half of d_out)
    Pre3 p3;
    p3.x = R; p3.g = ln3g; p3.bta = ln3b; p3.lnout = lnbuf;
    p3.w1 = m_w1; p3.wt1 = Wq;
    p3.w2 = m_w2; p3.wt2 = W2s;
    pre3_kernel<<<dim3(4096 + 2304 + 2304), tb, 0, stream>>>(p3);
    ga = GemmArgs{};
    ga.A[0] = lnbuf; ga.BT[0] = Wq; ga.bias[0] = m_b1; ga.out[0] = hb; ga.alpha[0] = 1.f;
    ga.M = 4096; ga.N = 3072; ga.K = 768;
    gemm_bt<2, 128><<<dim3(32, 24, 1), tb, 0, stream>>>(ga);
    ga = GemmArgs{};
    ga.A[0] = hb; ga.BT[0] = W2s; ga.bias[0] = m_b2; ga.res[0] = R; ga.out[0] = out_x; ga.alpha[0] = 1.f;
    ga.M = 4096; ga.N = 768; ga.K = 3072;
    gemm_bt<1, 64, 64><<<dim3(64, 12, 1), tb, 0, stream>>>(ga);
    // context passthrough LAST (d_out scratch roles all expired)
    hipMemcpyAsync(out_ctx, ctx, (size_t)NROWS * CDIM * 4,
                   hipMemcpyDeviceToDevice, stream);

    (void)in_sizes; (void)n_in; (void)out_size;
}

// Round 20
// 318.336 us; speedup vs baseline: 1.0874x; 1.0045x over previous
//
#include <hip/hip_runtime.h>
#include <hip/hip_bf16.h>
#include <math.h>

#define CDIM 768
#define HDIM 3072
#define NROWS 4096   // B*T
#define TSEQ 2048
#define NHEAD 12
#define KVSPLIT 4
#define KVLEN (TSEQ / KVSPLIT)   // 512 rows per part

typedef unsigned short u16;
typedef unsigned int   u32;
typedef __attribute__((ext_vector_type(8))) short short8;
typedef __attribute__((ext_vector_type(4))) float f32x4;

// 1/sqrt(64) * log2(e): folds the softmax ln->log2 conversion into Q
#define QSCALE 0.18033688011112042f

static __device__ __forceinline__ u16 f2bf(float f) {
    u32 x = __float_as_uint(f);
    x += 0x7fffu + ((x >> 16) & 1u);
    return (u16)(x >> 16);
}
static __device__ __forceinline__ float bf2f(u16 x) {
    return __uint_as_float((u32)x << 16);
}
static __device__ __forceinline__ u32 cvt_pk_bf16(float lo, float hi) {
    u32 r;
    asm("v_cvt_pk_bf16_f32 %0, %1, %2" : "=v"(r) : "v"(lo), "v"(hi));
    return r;
}

#define GLL16(g, l)                                                            \
    __builtin_amdgcn_global_load_lds(                                          \
        (const __attribute__((address_space(1))) void*)(g),                    \
        (__attribute__((address_space(3))) void*)(l), 16, 0, 0)

// ---------------------------------------------------------------- packed pre-work helpers
static __device__ void do_cvt(int blk, const float* __restrict__ in,
                              u16* __restrict__ out) {
    const int i = blk * 256 + threadIdx.x;   // float4 index, exact multiple
    float4 v = ((const float4*)in)[i];
    ushort4 o;
    o.x = f2bf(v.x); o.y = f2bf(v.y); o.z = f2bf(v.z); o.w = f2bf(v.w);
    ((ushort4*)out)[i] = o;
}

static __device__ void do_ln(int row, const float* __restrict__ x,
                             const float* __restrict__ g,
                             const float* __restrict__ bta,
                             u16* __restrict__ out, float* red) {
    const int tid = threadIdx.x;
    const float* xr = x + (size_t)row * CDIM;
    float v0 = xr[tid], v1 = xr[tid + 256], v2 = xr[tid + 512];
    float s = v0 + v1 + v2;
#pragma unroll
    for (int m = 1; m < 64; m <<= 1) s += __shfl_xor(s, m);
    if ((tid & 63) == 0) red[tid >> 6] = s;
    __syncthreads();
    const float mu = (red[0] + red[1] + red[2] + red[3]) * (1.f / CDIM);
    const float d0 = v0 - mu, d1 = v1 - mu, d2 = v2 - mu;
    float q = d0 * d0 + d1 * d1 + d2 * d2;
#pragma unroll
    for (int m = 1; m < 64; m <<= 1) q += __shfl_xor(q, m);
    if ((tid & 63) == 0) red[4 + (tid >> 6)] = q;
    __syncthreads();
    const float var = (red[4] + red[5] + red[6] + red[7]) * (1.f / CDIM);
    const float rstd = rsqrtf(var + 1e-5f);
    u16* orow = out + (size_t)row * CDIM;
    orow[tid]       = f2bf(d0 * rstd * g[tid]       + bta[tid]);
    orow[tid + 256] = f2bf(d1 * rstd * g[tid + 256] + bta[tid + 256]);
    orow[tid + 512] = f2bf(d2 * rstd * g[tid + 512] + bta[tid + 512]);
}

static __device__ void do_wt(int bx, int by, const float* __restrict__ w,
                             u16* __restrict__ wt, int K, int N, float* t /*32x33*/) {
    const int n0 = bx * 32, k0 = by * 32;
    const int tx = threadIdx.x & 31, ty = threadIdx.x >> 5;
#pragma unroll
    for (int i = ty; i < 32; i += 8)
        t[i * 33 + tx] = w[(size_t)(k0 + i) * N + n0 + tx];
    __syncthreads();
#pragma unroll
    for (int i = ty; i < 32; i += 8)
        wt[(size_t)(n0 + i) * K + k0 + tx] = f2bf(t[tx * 33 + i]);
}

// pre1: cvt_copy (3072) | LN1 (4096) | SA wtrans x4 (2304)
struct Pre1 {
    const float* ctx; u16* ctxb;
    const float* x; const float* g; const float* bta; u16* lnout;
    const float* w[4]; u16* wt[4];
};
__launch_bounds__(256)
__global__ void pre1_kernel(Pre1 p) {
    __shared__ float smem[32 * 33];
    int bid = blockIdx.x;
    if (bid < 3072) { do_cvt(bid, p.ctx, p.ctxb); return; }
    bid -= 3072;
    if (bid < 4096) { do_ln(bid, p.x, p.g, p.bta, p.lnout, smem); return; }
    bid -= 4096;
    const int z = bid / 576, rem = bid % 576;
    do_wt(rem % 24, rem / 24, p.w[z], p.wt[z], CDIM, CDIM, smem);
}

// pre2: LN (4096) | wtrans x4 (2304)
struct Pre2 {
    const float* x; const float* g; const float* bta; u16* lnout;
    const float* w[4]; u16* wt[4];
};
__launch_bounds__(256)
__global__ void pre2_kernel(Pre2 p) {
    __shared__ float smem[32 * 33];
    int bid = blockIdx.x;
    if (bid < 4096) { do_ln(bid, p.x, p.g, p.bta, p.lnout, smem); return; }
    bid -= 4096;
    const int z = bid / 576, rem = bid % 576;
    do_wt(rem % 24, rem / 24, p.w[z], p.wt[z], CDIM, CDIM, smem);
}

// pre3: LN3 (4096) | m_w1^T (2304: 96x24) | m_w2^T (2304: 24x96)
struct Pre3 {
    const float* x; const float* g; const float* bta; u16* lnout;
    const float* w1; u16* wt1;
    const float* w2; u16* wt2;
};
__launch_bounds__(256)
__global__ void pre3_kernel(Pre3 p) {
    __shared__ float smem[32 * 33];
    int bid = blockIdx.x;
    if (bid < 4096) { do_ln(bid, p.x, p.g, p.bta, p.lnout, smem); return; }
    bid -= 4096;
    if (bid < 2304) { do_wt(bid % 96, bid / 96, p.w1, p.wt1, CDIM, HDIM, smem); return; }
    bid -= 2304;
    do_wt(bid % 24, bid / 24, p.w2, p.wt2, HDIM, CDIM, smem);
}

// ---------------------------------------------------------------- GEMM (R17-verified)
struct GemmArgs {
    const u16* A[3];
    const u16* BT[3];
    const float* bias[3];
    const float* res[3];
    void* out[3];
    float alpha[3];
    int M, N, K;
};

// EPI: 0 = (s+bias)*alpha -> bf16 ; 1 = res + s + bias -> f32 ; 2 = gelu -> bf16
template <int EPI, int BM, int BN = 128>
__launch_bounds__(256, 4)
__global__ void gemm_bt(GemmArgs ga) {
    constexpr int MF = BM / 32, NF = BN / 32;
    __shared__ u16 Abuf[BM * 32];
    __shared__ u16 Bbuf[BN * 32];
    const int z = blockIdx.z;
    const u16* __restrict__ A  = ga.A[z];
    const u16* __restrict__ BT = ga.BT[z];
    const float* __restrict__ bias = ga.bias[z];
    const float* __restrict__ res  = ga.res[z];
    void* outv = ga.out[z];
    const float alpha = ga.alpha[z];
    const int N = ga.N, K = ga.K;

    const int tid = threadIdx.x;
    const int lane = tid & 63, w = tid >> 6;
    const int m0 = blockIdx.x * BM, n0 = blockIdx.y * BN;
    const int wr = (w >> 1) * (BM / 2), wc = (w & 1) * (BN / 2);
    const int lr = lane & 15, lc = lane >> 4;

    const int srowA = (BM == 128) ? (w * 32 + (lane >> 2)) : (tid >> 2);
    const int srowB = (BN == 128) ? (w * 32 + (lane >> 2)) : (tid >> 2);
    const int scol = (lane & 3) * 8;
    const u16* Ag = A + (size_t)(m0 + srowA) * K + scol;
    const u16* Bg = BT + (size_t)(n0 + srowB) * K + scol;
    char* Ab = (char*)Abuf + w * (BM == 128 ? 2048 : 1024);
    char* Bb = (char*)Bbuf + w * (BN == 128 ? 2048 : 1024);

    f32x4 acc[MF][NF];
#pragma unroll
    for (int m = 0; m < MF; ++m)
#pragma unroll
        for (int n = 0; n < NF; ++n) acc[m][n] = (f32x4){0.f, 0.f, 0.f, 0.f};

    const int nk = K >> 5;
    for (int kt = 0; kt < nk; ++kt) {
        const int ko = kt * 32;
        GLL16(Ag + ko, Ab);
        if constexpr (BM == 128) GLL16(Ag + 16 * K + ko, Ab + 1024);
        GLL16(Bg + ko, Bb);
        if constexpr (BN == 128) GLL16(Bg + 16 * K + ko, Bb + 1024);
        __syncthreads();
        short8 af[MF], bfv[NF];
#pragma unroll
        for (int m = 0; m < MF; ++m)
            af[m] = *(const short8*)((const char*)Abuf +
                                     (size_t)(wr + m * 16 + lr) * 64 + lc * 16);
#pragma unroll
        for (int n = 0; n < NF; ++n)
            bfv[n] = *(const short8*)((const char*)Bbuf +
                                      (size_t)(wc + n * 16 + lr) * 64 + lc * 16);
#pragma unroll
        for (int m = 0; m < MF; ++m)
#pragma unroll
            for (int n = 0; n < NF; ++n)
                acc[m][n] = __builtin_amdgcn_mfma_f32_16x16x32_bf16(
                    af[m], bfv[n], acc[m][n], 0, 0, 0);
        __syncthreads();
    }

#pragma unroll
    for (int n = 0; n < NF; ++n) {
        const int gc = n0 + wc + n * 16 + lr;
        const float bs = bias[gc];
#pragma unroll
        for (int m = 0; m < MF; ++m) {
            const int gr = m0 + wr + m * 16 + lc * 4;
#pragma unroll
            for (int r = 0; r < 4; ++r) {
                float v = (acc[m][n][r] + bs) * alpha;
                const size_t idx = (size_t)(gr + r) * N + gc;
                if constexpr (EPI == 0) {
                    ((u16*)outv)[idx] = f2bf(v);
                } else if constexpr (EPI == 1) {
                    ((float*)outv)[idx] = res[idx] + v;
                } else {
                    float gel = 0.5f * v * (1.0f + erff(v * 0.70710678118654752f));
                    ((u16*)outv)[idx] = f2bf(gel);
                }
            }
        }
    }
}

// ---------------------------------------------------------------- attention helpers
// l is accumulated via the matrix pipe (ones-row trick): caller adds
// mfma(ones, P, lacc) in the PV section; this helper only handles max,
// rescale (incl. lacc), exp2, and P packing.
static __device__ __forceinline__ void softmax_pack(f32x4 sf[4], float& mrow,
                                                    f32x4& lacc, f32x4 oacc[4],
                                                    short8& p0, short8& p1) {
    float pm;
    {
        float a0 = fmaxf(fmaxf(sf[0][0], sf[0][1]), fmaxf(sf[0][2], sf[0][3]));
        float a1 = fmaxf(fmaxf(sf[1][0], sf[1][1]), fmaxf(sf[1][2], sf[1][3]));
        float a2 = fmaxf(fmaxf(sf[2][0], sf[2][1]), fmaxf(sf[2][2], sf[2][3]));
        float a3 = fmaxf(fmaxf(sf[3][0], sf[3][1]), fmaxf(sf[3][2], sf[3][3]));
        pm = fmaxf(fmaxf(a0, a1), fmaxf(a2, a3));
        pm = fmaxf(pm, __shfl_xor(pm, 16));
        pm = fmaxf(pm, __shfl_xor(pm, 32));
    }
    // defer-max: only rescale when some q-row's max grew (wave-uniform)
    if (!__all(pm <= mrow)) {
        const float mn = fmaxf(mrow, pm);
        const float corr = exp2f(mrow - mn);
        mrow = mn;
#pragma unroll
        for (int r = 0; r < 4; ++r) lacc[r] *= corr;
#pragma unroll
        for (int fd = 0; fd < 4; ++fd)
#pragma unroll
            for (int r = 0; r < 4; ++r) oacc[fd][r] *= corr;
    }
#pragma unroll
    for (int fn = 0; fn < 4; ++fn)
#pragma unroll
        for (int r = 0; r < 4; ++r) sf[fn][r] = exp2f(sf[fn][r] - mrow);
    int4 pw0, pw1;
    pw0.x = cvt_pk_bf16(sf[0][0], sf[0][1]);
    pw0.y = cvt_pk_bf16(sf[0][2], sf[0][3]);
    pw0.z = cvt_pk_bf16(sf[1][0], sf[1][1]);
    pw0.w = cvt_pk_bf16(sf[1][2], sf[1][3]);
    pw1.x = cvt_pk_bf16(sf[2][0], sf[2][1]);
    pw1.y = cvt_pk_bf16(sf[2][2], sf[2][3]);
    pw1.z = cvt_pk_bf16(sf[3][0], sf[3][1]);
    pw1.w = cvt_pk_bf16(sf[3][2], sf[3][3]);
    p0 = *(short8*)&pw0;
    p1 = *(short8*)&pw1;
}

// ---------------------------------------------------------------- attention (split-KV, 128q/block)
__launch_bounds__(256, 4)
__global__ void attn_split(const u16* __restrict__ Qb, const u16* __restrict__ Kb,
                           const u16* __restrict__ Vb, u16* __restrict__ Opart,
                           float2* __restrict__ ml) {
    __shared__ u16 Klds[64 * 72];
    __shared__ u16 Vt[64 * 72];
    const int tid = threadIdx.x;
    const int lane = tid & 63, w = tid >> 6;
    const int lr = lane & 15, lc = lane >> 4;
    const int b = blockIdx.y / NHEAD, h = blockIdx.y % NHEAD;
    const int z = blockIdx.z;
    const size_t qrowA = (size_t)b * TSEQ + blockIdx.x * 128 + w * 16;
    const size_t qrowB = qrowA + 64;
    const size_t krow0 = (size_t)b * TSEQ + (size_t)z * KVLEN;
    const int hc = h * 64;

    short8 qa0, qa1, qb0, qb1;
    {
        const u16* qp = Qb + (qrowA + lr) * CDIM + hc + lc * 8;
        qa0 = *(const short8*)qp;
        qa1 = *(const short8*)(qp + 32);
        const u16* qp2 = Qb + (qrowB + lr) * CDIM + hc + lc * 8;
        qb0 = *(const short8*)qp2;
        qb1 = *(const short8*)(qp2 + 32);
    }
    // ones A-fragment (bf16 1.0 in every slot) for the l-accumulation MFMAs
    short8 ones;
    {
        int4 ow = {0x3F803F80, 0x3F803F80, 0x3F803F80, 0x3F803F80};
        ones = *(short8*)&ow;
    }
    f32x4 oaccA[4], oaccB[4], laccA, laccB;
#pragma unroll
    for (int r = 0; r < 4; ++r) {
        oaccA[r] = (f32x4){0.f, 0.f, 0.f, 0.f};
        oaccB[r] = (f32x4){0.f, 0.f, 0.f, 0.f};
    }
    laccA = (f32x4){0.f, 0.f, 0.f, 0.f};
    laccB = (f32x4){0.f, 0.f, 0.f, 0.f};
    float mA = -3e38f, mB = -3e38f;

    const int stg_r = tid >> 2, stg_s = tid & 3;
    const u16* kg = Kb + (krow0 + stg_r) * CDIM + hc + stg_s * 16;
    const u16* vg = Vb + (krow0 + stg_r) * CDIM + hc + stg_s * 16;
    uint4 ka0 = *(const uint4*)kg, ka1 = *(const uint4*)(kg + 8);
    uint4 va0 = *(const uint4*)vg, va1 = *(const uint4*)(vg + 8);
    const int sig = ((stg_r >> 5) << 5) + (((stg_r >> 2) & 3) << 3) +
                    (((stg_r >> 4) & 1) << 2) + (stg_r & 3);
    char* vdst = (char*)Vt + ((2 * sig) ^ (stg_s << 5)) +
                 (size_t)(stg_s * 16) * 144;

    for (int kt = 0; kt < KVLEN / 64; ++kt) {
        __syncthreads();
        {
            *(uint4*)&Klds[stg_r * 72 + stg_s * 16]     = ka0;
            *(uint4*)&Klds[stg_r * 72 + stg_s * 16 + 8] = ka1;
            u16 tmp[16];
            *(uint4*)(tmp)     = va0;
            *(uint4*)(tmp + 8) = va1;
#pragma unroll
            for (int j = 0; j < 16; ++j)
                *(u16*)(vdst + (size_t)j * 144) = tmp[j];
        }
        if (kt < KVLEN / 64 - 1) {
            kg += 64 * CDIM; vg += 64 * CDIM;
            ka0 = *(const uint4*)kg; ka1 = *(const uint4*)(kg + 8);
            va0 = *(const uint4*)vg; va1 = *(const uint4*)(vg + 8);
        }
        __syncthreads();

        // S^T = K * Q^T for both q-groups; each K fragment read used twice
        f32x4 sfA[4], sfB[4];
#pragma unroll
        for (int fn = 0; fn < 4; ++fn) {
            const u16* kr = &Klds[(lr + fn * 16) * 72 + lc * 8];
            short8 kb0 = *(const short8*)kr;
            short8 kb1 = *(const short8*)(kr + 32);
            f32x4 t = (f32x4){0.f, 0.f, 0.f, 0.f};
            t = __builtin_amdgcn_mfma_f32_16x16x32_bf16(kb0, qa0, t, 0, 0, 0);
            t = __builtin_amdgcn_mfma_f32_16x16x32_bf16(kb1, qa1, t, 0, 0, 0);
            sfA[fn] = t;
            f32x4 u = (f32x4){0.f, 0.f, 0.f, 0.f};
            u = __builtin_amdgcn_mfma_f32_16x16x32_bf16(kb0, qb0, u, 0, 0, 0);
            u = __builtin_amdgcn_mfma_f32_16x16x32_bf16(kb1, qb1, u, 0, 0, 0);
            sfB[fn] = u;
        }

        short8 pA0, pA1, pB0, pB1;
        softmax_pack(sfA, mA, laccA, oaccA, pA0, pA1);
        softmax_pack(sfB, mB, laccB, oaccB, pB0, pB1);

        // l accumulation on the matrix pipe: D[r][q] = sum_k P[k][q]
        laccA = __builtin_amdgcn_mfma_f32_16x16x32_bf16(ones, pA0, laccA, 0, 0, 0);
        laccA = __builtin_amdgcn_mfma_f32_16x16x32_bf16(ones, pA1, laccA, 0, 0, 0);
        laccB = __builtin_amdgcn_mfma_f32_16x16x32_bf16(ones, pB0, laccB, 0, 0, 0);
        laccB = __builtin_amdgcn_mfma_f32_16x16x32_bf16(ones, pB1, laccB, 0, 0, 0);

        // O^T += V^T * P^T ; each V fragment read used twice
#pragma unroll
        for (int fd = 0; fd < 4; ++fd) {
            const char* vtb = (const char*)Vt + (size_t)(lr + fd * 16) * 144;
            short8 vb0 = *(const short8*)(vtb + ((lc * 16) ^ (fd * 32)));
            short8 vb1 = *(const short8*)(vtb + ((lc * 16 + 64) ^ (fd * 32)));
            oaccA[fd] = __builtin_amdgcn_mfma_f32_16x16x32_bf16(vb0, pA0, oaccA[fd], 0, 0, 0);
            oaccA[fd] = __builtin_amdgcn_mfma_f32_16x16x32_bf16(vb1, pA1, oaccA[fd], 0, 0, 0);
            oaccB[fd] = __builtin_amdgcn_mfma_f32_16x16x32_bf16(vb0, pB0, oaccB[fd], 0, 0, 0);
            oaccB[fd] = __builtin_amdgcn_mfma_f32_16x16x32_bf16(vb1, pB1, oaccB[fd], 0, 0, 0);
        }
    }

    // epilogue: UNNORMALIZED bf16 partials + (m,l) for both groups.
    // lacc rows are all equal: l[q=lr] = lacc[any r].
    u16* oA = Opart + (size_t)z * NROWS * CDIM + (qrowA + lr) * CDIM + hc + lc * 4;
    u16* oB = Opart + (size_t)z * NROWS * CDIM + (qrowB + lr) * CDIM + hc + lc * 4;
#pragma unroll
    for (int fd = 0; fd < 4; ++fd) {
        ushort4 o;
        o.x = f2bf(oaccA[fd][0]); o.y = f2bf(oaccA[fd][1]);
        o.z = f2bf(oaccA[fd][2]); o.w = f2bf(oaccA[fd][3]);
        *(ushort4*)(oA + fd * 16) = o;
        o.x = f2bf(oaccB[fd][0]); o.y = f2bf(oaccB[fd][1]);
        o.z = f2bf(oaccB[fd][2]); o.w = f2bf(oaccB[fd][3]);
        *(ushort4*)(oB + fd * 16) = o;
    }
    if (lc == 0) {
        ml[((size_t)z * NROWS + qrowA + lr) * NHEAD + h] = (float2){mA, laccA[0]};
        ml[((size_t)z * NROWS + qrowB + lr) * NHEAD + h] = (float2){mB, laccB[0]};
    }
}

// ---------------------------------------------------------------- merge (4 parts)
__launch_bounds__(256)
__global__ void attn_merge4(const u16* __restrict__ P, const float2* __restrict__ ml,
                            u16* __restrict__ out) {
    const int i4 = blockIdx.x * 256 + threadIdx.x;   // 4-elem chunk index
    const size_t base = (size_t)i4 * 4;
    const int row = (int)(base / CDIM);
    const int head = (int)(base - (size_t)row * CDIM) >> 6;
    float2 a[KVSPLIT];
    float M = -3e38f;
#pragma unroll
    for (int z = 0; z < KVSPLIT; ++z) {
        a[z] = ml[((size_t)z * NROWS + row) * NHEAD + head];
        M = fmaxf(M, a[z].x);
    }
    float den = 0.f, e[KVSPLIT];
#pragma unroll
    for (int z = 0; z < KVSPLIT; ++z) {
        e[z] = exp2f(a[z].x - M);
        den += a[z].y * e[z];
    }
    const float rden = 1.f / den;
    float o0 = 0.f, o1 = 0.f, o2 = 0.f, o3 = 0.f;
#pragma unroll
    for (int z = 0; z < KVSPLIT; ++z) {
        ushort4 p = *(const ushort4*)(P + (size_t)z * NROWS * CDIM + base);
        o0 += bf2f(p.x) * e[z];
        o1 += bf2f(p.y) * e[z];
        o2 += bf2f(p.z) * e[z];
        o3 += bf2f(p.w) * e[z];
    }
    ushort4 o;
    o.x = f2bf(o0 * rden); o.y = f2bf(o1 * rden);
    o.z = f2bf(o2 * rden); o.w = f2bf(o3 * rden);
    *(ushort4*)(out + base) = o;
}

// ---------------------------------------------------------------- launch
extern "C" void kernel_launch(void* const* d_in, const int* in_sizes, int n_in,
                              void* d_out, int out_size, void* d_ws, size_t ws_size,
                              hipStream_t stream) {
    const float* x     = (const float*)d_in[0];
    const float* ctx   = (const float*)d_in[1];
    const float* ln1g  = (const float*)d_in[2];
    const float* ln1b  = (const float*)d_in[3];
    const float* ln2g  = (const float*)d_in[4];
    const float* ln2b  = (const float*)d_in[5];
    const float* ln3g  = (const float*)d_in[6];
    const float* ln3b  = (const float*)d_in[7];
    const float* sa_wq = (const float*)d_in[8];
    const float* sa_bq = (const float*)d_in[9];
    const float* sa_wk = (const float*)d_in[10];
    const float* sa_bk = (const float*)d_in[11];
    const float* sa_wv = (const float*)d_in[12];
    const float* sa_bv = (const float*)d_in[13];
    const float* sa_wo = (const float*)d_in[14];
    const float* sa_bo = (const float*)d_in[15];
    const float* xa_wq = (const float*)d_in[16];
    const float* xa_bq = (const float*)d_in[17];
    const float* xa_wk = (const float*)d_in[18];
    const float* xa_bk = (const float*)d_in[19];
    const float* xa_wv = (const float*)d_in[20];
    const float* xa_bv = (const float*)d_in[21];
    const float* xa_wo = (const float*)d_in[22];
    const float* xa_bo = (const float*)d_in[23];
    const float* m_w1  = (const float*)d_in[24];
    const float* m_b1  = (const float*)d_in[25];
    const float* m_w2  = (const float*)d_in[26];
    const float* m_b2  = (const float*)d_in[27];

    float* out_x   = (float*)d_out;
    float* out_ctx = out_x + (size_t)NROWS * CDIM;
    // d_out doubles as scratch: bf16 split-KV partials during attention,
    // then m_w2^T (4.7MB, in the out_ctx half) during the MLP. The ctx
    // passthrough memcpy is the LAST op.
    u16* Opart = (u16*)d_out;
    u16* W2s   = (u16*)out_ctx;

    const size_t SZ_ACT  = (size_t)NROWS * CDIM * 2;
    const size_t SZ_WBIG = (size_t)HDIM * CDIM * 2;
    const size_t SZ_R    = (size_t)NROWS * CDIM * 4;
    const size_t NEEDED  = 5 * SZ_ACT + SZ_R + SZ_WBIG;
    if (ws_size < NEEDED) return;

    char* ws = (char*)d_ws;
    u16* qb    = (u16*)(ws);
    u16* kb    = (u16*)(ws + 1 * SZ_ACT);
    u16* vb    = (u16*)(ws + 2 * SZ_ACT);
    u16* ctxb  = (u16*)(ws + 3 * SZ_ACT);
    u16* hb    = qb;
    u16* lnbuf = (u16*)(ws + 4 * SZ_ACT);
    u16* attB  = lnbuf;
    float* R   = (float*)(ws + 5 * SZ_ACT);
    u16* Wq    = (u16*)(ws + 5 * SZ_ACT + SZ_R);   // pool: [Wq][Wk][Wv][Wo]
    u16* Wk    = Wq + (size_t)CDIM * CDIM;
    u16* Wv    = Wk + (size_t)CDIM * CDIM;
    u16* Wo    = Wv + (size_t)CDIM * CDIM;
    // ml (1.57MB) overlays Wq+Wk (dead after the QKV GEMM); Wo survives.
    float2* ml = (float2*)Wq;

    const dim3 tb(256);
    GemmArgs ga;

    // ---- self-attention
    Pre1 p1;
    p1.ctx = ctx; p1.ctxb = ctxb;
    p1.x = x; p1.g = ln1g; p1.bta = ln1b; p1.lnout = lnbuf;
    p1.w[0] = sa_wq; p1.w[1] = sa_wk; p1.w[2] = sa_wv; p1.w[3] = sa_wo;
    p1.wt[0] = Wq;   p1.wt[1] = Wk;   p1.wt[2] = Wv;   p1.wt[3] = Wo;
    pre1_kernel<<<dim3(3072 + 4096 + 2304), tb, 0, stream>>>(p1);
    ga = GemmArgs{};
    ga.A[0] = lnbuf; ga.BT[0] = Wq; ga.bias[0] = sa_bq; ga.out[0] = qb; ga.alpha[0] = QSCALE;
    ga.A[1] = lnbuf; ga.BT[1] = Wk; ga.bias[1] = sa_bk; ga.out[1] = kb; ga.alpha[1] = 1.f;
    ga.A[2] = lnbuf; ga.BT[2] = Wv; ga.bias[2] = sa_bv; ga.out[2] = vb; ga.alpha[2] = 1.f;
    ga.M = 4096; ga.N = 768; ga.K = 768;
    gemm_bt<0, 128, 64><<<dim3(32, 12, 3), tb, 0, stream>>>(ga);
    attn_split<<<dim3(16, 24, KVSPLIT), tb, 0, stream>>>(qb, kb, vb, Opart, ml);
    attn_merge4<<<dim3(NROWS * CDIM / 1024), tb, 0, stream>>>(Opart, ml, attB);
    ga = GemmArgs{};
    ga.A[0] = attB; ga.BT[0] = Wo; ga.bias[0] = sa_bo; ga.res[0] = x; ga.out[0] = R; ga.alpha[0] = 1.f;
    ga.M = 4096; ga.N = 768; ga.K = 768;
    gemm_bt<1, 64, 64><<<dim3(64, 12, 1), tb, 0, stream>>>(ga);

    // ---- cross-attention
    Pre2 p2;
    p2.x = R; p2.g = ln2g; p2.bta = ln2b; p2.lnout = lnbuf;
    p2.w[0] = xa_wq; p2.w[1] = xa_wk; p2.w[2] = xa_wv; p2.w[3] = xa_wo;
    p2.wt[0] = Wq;   p2.wt[1] = Wk;   p2.wt[2] = Wv;   p2.wt[3] = Wo;
    pre2_kernel<<<dim3(4096 + 2304), tb, 0, stream>>>(p2);
    ga = GemmArgs{};
    ga.A[0] = lnbuf; ga.BT[0] = Wq; ga.bias[0] = xa_bq; ga.out[0] = qb; ga.alpha[0] = QSCALE;
    ga.A[1] = ctxb;  ga.BT[1] = Wk; ga.bias[1] = xa_bk; ga.out[1] = kb; ga.alpha[1] = 1.f;
    ga.A[2] = ctxb;  ga.BT[2] = Wv; ga.bias[2] = xa_bv; ga.out[2] = vb; ga.alpha[2] = 1.f;
    ga.M = 4096; ga.N = 768; ga.K = 768;
    gemm_bt<0, 128, 64><<<dim3(32, 12, 3), tb, 0, stream>>>(ga);
    attn_split<<<dim3(16, 24, KVSPLIT), tb, 0, stream>>>(qb, kb, vb, Opart, ml);
    attn_merge4<<<dim3(NROWS * CDIM / 1024), tb, 0, stream>>>(Opart, ml, attB);
    ga = GemmArgs{};
    ga.A[0] = attB; ga.BT[0] = Wo; ga.bias[0] = xa_bo; ga.res[0] = R; ga.out[0] = R; ga.alpha[0] = 1.f;
    ga.M = 4096; ga.N = 768; ga.K = 768;
    gemm_bt<1, 64, 64><<<dim3(64, 12, 1), tb, 0, stream>>>(ga);

    // ---- MLP (m_w2^T staged in the dead out_ctx half of d_out)
    Pre3 p3;
    p3.x = R; p3.g = ln3g; p3.bta = ln3b; p3.lnout = lnbuf;
    p3.w1 = m_w1; p3.wt1 = Wq;
    p3.w2 = m_w2; p3.wt2 = W2s;
    pre3_kernel<<<dim3(4096 + 2304 + 2304), tb, 0, stream>>>(p3);
    ga = GemmArgs{};
    ga.A[0] = lnbuf; ga.BT[0] = Wq; ga.bias[0] = m_b1; ga.out[0] = hb; ga.alpha[0] = 1.f;
    ga.M = 4096; ga.N = 3072; ga.K = 768;
    gemm_bt<2, 128><<<dim3(32, 24, 1), tb, 0, stream>>>(ga);
    ga = GemmArgs{};
    ga.A[0] = hb; ga.BT[0] = W2s; ga.bias[0] = m_b2; ga.res[0] = R; ga.out[0] = out_x; ga.alpha[0] = 1.f;
    ga.M = 4096; ga.N = 768; ga.K = 3072;
    gemm_bt<1, 64, 64><<<dim3(64, 12, 1), tb, 0, stream>>>(ga);
    // context passthrough LAST (d_out scratch roles all expired)
    hipMemcpyAsync(out_ctx, ctx, (size_t)NROWS * CDIM * 4,
                   hipMemcpyDeviceToDevice, stream);

    (void)in_sizes; (void)n_in; (void)out_size;
}

// Round 21
// 318.290 us; speedup vs baseline: 1.0875x; 1.0001x over previous
//
#include <hip/hip_runtime.h>
#include <hip/hip_bf16.h>
#include <math.h>

#define CDIM 768
#define HDIM 3072
#define NROWS 4096   // B*T
#define TSEQ 2048
#define NHEAD 12
#define KVSPLIT 4
#define KVLEN (TSEQ / KVSPLIT)   // 512 rows per part

typedef unsigned short u16;
typedef unsigned int   u32;
typedef __attribute__((ext_vector_type(8))) short short8;
typedef __attribute__((ext_vector_type(4))) float f32x4;

// 1/sqrt(64) * log2(e): folds the softmax ln->log2 conversion into Q
#define QSCALE 0.18033688011112042f

static __device__ __forceinline__ u16 f2bf(float f) {
    u32 x = __float_as_uint(f);
    x += 0x7fffu + ((x >> 16) & 1u);
    return (u16)(x >> 16);
}
static __device__ __forceinline__ float bf2f(u16 x) {
    return __uint_as_float((u32)x << 16);
}
static __device__ __forceinline__ u32 cvt_pk_bf16(float lo, float hi) {
    u32 r;
    asm("v_cvt_pk_bf16_f32 %0, %1, %2" : "=v"(r) : "v"(lo), "v"(hi));
    return r;
}

#define GLL16(g, l)                                                            \
    __builtin_amdgcn_global_load_lds(                                          \
        (const __attribute__((address_space(1))) void*)(g),                    \
        (__attribute__((address_space(3))) void*)(l), 16, 0, 0)

// ---------------------------------------------------------------- packed pre-work helpers
static __device__ void do_cvt(int blk, const float* __restrict__ in,
                              u16* __restrict__ out) {
    const int i = blk * 256 + threadIdx.x;   // float4 index, exact multiple
    float4 v = ((const float4*)in)[i];
    ushort4 o;
    o.x = f2bf(v.x); o.y = f2bf(v.y); o.z = f2bf(v.z); o.w = f2bf(v.w);
    ((ushort4*)out)[i] = o;
}

static __device__ void do_ln(int row, const float* __restrict__ x,
                             const float* __restrict__ g,
                             const float* __restrict__ bta,
                             u16* __restrict__ out, float* red) {
    const int tid = threadIdx.x;
    const float* xr = x + (size_t)row * CDIM;
    float v0 = xr[tid], v1 = xr[tid + 256], v2 = xr[tid + 512];
    float s = v0 + v1 + v2;
#pragma unroll
    for (int m = 1; m < 64; m <<= 1) s += __shfl_xor(s, m);
    if ((tid & 63) == 0) red[tid >> 6] = s;
    __syncthreads();
    const float mu = (red[0] + red[1] + red[2] + red[3]) * (1.f / CDIM);
    const float d0 = v0 - mu, d1 = v1 - mu, d2 = v2 - mu;
    float q = d0 * d0 + d1 * d1 + d2 * d2;
#pragma unroll
    for (int m = 1; m < 64; m <<= 1) q += __shfl_xor(q, m);
    if ((tid & 63) == 0) red[4 + (tid >> 6)] = q;
    __syncthreads();
    const float var = (red[4] + red[5] + red[6] + red[7]) * (1.f / CDIM);
    const float rstd = rsqrtf(var + 1e-5f);
    u16* orow = out + (size_t)row * CDIM;
    orow[tid]       = f2bf(d0 * rstd * g[tid]       + bta[tid]);
    orow[tid + 256] = f2bf(d1 * rstd * g[tid + 256] + bta[tid + 256]);
    orow[tid + 512] = f2bf(d2 * rstd * g[tid + 512] + bta[tid + 512]);
}

static __device__ void do_wt(int bx, int by, const float* __restrict__ w,
                             u16* __restrict__ wt, int K, int N, float* t /*32x33*/) {
    const int n0 = bx * 32, k0 = by * 32;
    const int tx = threadIdx.x & 31, ty = threadIdx.x >> 5;
#pragma unroll
    for (int i = ty; i < 32; i += 8)
        t[i * 33 + tx] = w[(size_t)(k0 + i) * N + n0 + tx];
    __syncthreads();
#pragma unroll
    for (int i = ty; i < 32; i += 8)
        wt[(size_t)(n0 + i) * K + k0 + tx] = f2bf(t[tx * 33 + i]);
}

// pre1: cvt_copy (3072) | LN1 (4096) | SA wtrans x4 (2304)
struct Pre1 {
    const float* ctx; u16* ctxb;
    const float* x; const float* g; const float* bta; u16* lnout;
    const float* w[4]; u16* wt[4];
};
__launch_bounds__(256)
__global__ void pre1_kernel(Pre1 p) {
    __shared__ float smem[32 * 33];
    int bid = blockIdx.x;
    if (bid < 3072) { do_cvt(bid, p.ctx, p.ctxb); return; }
    bid -= 3072;
    if (bid < 4096) { do_ln(bid, p.x, p.g, p.bta, p.lnout, smem); return; }
    bid -= 4096;
    const int z = bid / 576, rem = bid % 576;
    do_wt(rem % 24, rem / 24, p.w[z], p.wt[z], CDIM, CDIM, smem);
}

// pre2: LN (4096) | wtrans x4 (2304)
struct Pre2 {
    const float* x; const float* g; const float* bta; u16* lnout;
    const float* w[4]; u16* wt[4];
};
__launch_bounds__(256)
__global__ void pre2_kernel(Pre2 p) {
    __shared__ float smem[32 * 33];
    int bid = blockIdx.x;
    if (bid < 4096) { do_ln(bid, p.x, p.g, p.bta, p.lnout, smem); return; }
    bid -= 4096;
    const int z = bid / 576, rem = bid % 576;
    do_wt(rem % 24, rem / 24, p.w[z], p.wt[z], CDIM, CDIM, smem);
}

// pre3: LN3 (4096) | m_w1^T (2304: 96x24) | m_w2^T (2304: 24x96)
struct Pre3 {
    const float* x; const float* g; const float* bta; u16* lnout;
    const float* w1; u16* wt1;
    const float* w2; u16* wt2;
};
__launch_bounds__(256)
__global__ void pre3_kernel(Pre3 p) {
    __shared__ float smem[32 * 33];
    int bid = blockIdx.x;
    if (bid < 4096) { do_ln(bid, p.x, p.g, p.bta, p.lnout, smem); return; }
    bid -= 4096;
    if (bid < 2304) { do_wt(bid % 96, bid / 96, p.w1, p.wt1, CDIM, HDIM, smem); return; }
    bid -= 2304;
    do_wt(bid % 24, bid / 24, p.w2, p.wt2, HDIM, CDIM, smem);
}

// ---------------------------------------------------------------- GEMM (R17-verified)
struct GemmArgs {
    const u16* A[3];
    const u16* BT[3];
    const float* bias[3];
    const float* res[3];
    void* out[3];
    float alpha[3];
    int M, N, K;
};

// EPI: 0 = (s+bias)*alpha -> bf16 ; 1 = res + s + bias -> f32 ; 2 = gelu -> bf16
template <int EPI, int BM, int BN = 128>
__launch_bounds__(256, 4)
__global__ void gemm_bt(GemmArgs ga) {
    constexpr int MF = BM / 32, NF = BN / 32;
    __shared__ u16 Abuf[BM * 32];
    __shared__ u16 Bbuf[BN * 32];
    const int z = blockIdx.z;
    const u16* __restrict__ A  = ga.A[z];
    const u16* __restrict__ BT = ga.BT[z];
    const float* __restrict__ bias = ga.bias[z];
    const float* __restrict__ res  = ga.res[z];
    void* outv = ga.out[z];
    const float alpha = ga.alpha[z];
    const int N = ga.N, K = ga.K;

    const int tid = threadIdx.x;
    const int lane = tid & 63, w = tid >> 6;
    const int m0 = blockIdx.x * BM, n0 = blockIdx.y * BN;
    const int wr = (w >> 1) * (BM / 2), wc = (w & 1) * (BN / 2);
    const int lr = lane & 15, lc = lane >> 4;

    const int srowA = (BM == 128) ? (w * 32 + (lane >> 2)) : (tid >> 2);
    const int srowB = (BN == 128) ? (w * 32 + (lane >> 2)) : (tid >> 2);
    const int scol = (lane & 3) * 8;
    const u16* Ag = A + (size_t)(m0 + srowA) * K + scol;
    const u16* Bg = BT + (size_t)(n0 + srowB) * K + scol;
    char* Ab = (char*)Abuf + w * (BM == 128 ? 2048 : 1024);
    char* Bb = (char*)Bbuf + w * (BN == 128 ? 2048 : 1024);

    f32x4 acc[MF][NF];
#pragma unroll
    for (int m = 0; m < MF; ++m)
#pragma unroll
        for (int n = 0; n < NF; ++n) acc[m][n] = (f32x4){0.f, 0.f, 0.f, 0.f};

    const int nk = K >> 5;
    for (int kt = 0; kt < nk; ++kt) {
        const int ko = kt * 32;
        GLL16(Ag + ko, Ab);
        if constexpr (BM == 128) GLL16(Ag + 16 * K + ko, Ab + 1024);
        GLL16(Bg + ko, Bb);
        if constexpr (BN == 128) GLL16(Bg + 16 * K + ko, Bb + 1024);
        __syncthreads();
        short8 af[MF], bfv[NF];
#pragma unroll
        for (int m = 0; m < MF; ++m)
            af[m] = *(const short8*)((const char*)Abuf +
                                     (size_t)(wr + m * 16 + lr) * 64 + lc * 16);
#pragma unroll
        for (int n = 0; n < NF; ++n)
            bfv[n] = *(const short8*)((const char*)Bbuf +
                                      (size_t)(wc + n * 16 + lr) * 64 + lc * 16);
#pragma unroll
        for (int m = 0; m < MF; ++m)
#pragma unroll
            for (int n = 0; n < NF; ++n)
                acc[m][n] = __builtin_amdgcn_mfma_f32_16x16x32_bf16(
                    af[m], bfv[n], acc[m][n], 0, 0, 0);
        __syncthreads();
    }

#pragma unroll
    for (int n = 0; n < NF; ++n) {
        const int gc = n0 + wc + n * 16 + lr;
        const float bs = bias[gc];
#pragma unroll
        for (int m = 0; m < MF; ++m) {
            const int gr = m0 + wr + m * 16 + lc * 4;
#pragma unroll
            for (int r = 0; r < 4; ++r) {
                float v = (acc[m][n][r] + bs) * alpha;
                const size_t idx = (size_t)(gr + r) * N + gc;
                if constexpr (EPI == 0) {
                    ((u16*)outv)[idx] = f2bf(v);
                } else if constexpr (EPI == 1) {
                    ((float*)outv)[idx] = res[idx] + v;
                } else {
                    float gel = 0.5f * v * (1.0f + erff(v * 0.70710678118654752f));
                    ((u16*)outv)[idx] = f2bf(gel);
                }
            }
        }
    }
}

// ---------------------------------------------------------------- attention helpers
// l is accumulated via the matrix pipe (ones-row trick): caller adds
// mfma(ones, P, lacc) in the PV section; this helper only handles max,
// rescale (incl. lacc), exp2, and P packing.
static __device__ __forceinline__ void softmax_pack(f32x4 sf[4], float& mrow,
                                                    f32x4& lacc, f32x4 oacc[4],
                                                    short8& p0, short8& p1) {
    float pm;
    {
        float a0 = fmaxf(fmaxf(sf[0][0], sf[0][1]), fmaxf(sf[0][2], sf[0][3]));
        float a1 = fmaxf(fmaxf(sf[1][0], sf[1][1]), fmaxf(sf[1][2], sf[1][3]));
        float a2 = fmaxf(fmaxf(sf[2][0], sf[2][1]), fmaxf(sf[2][2], sf[2][3]));
        float a3 = fmaxf(fmaxf(sf[3][0], sf[3][1]), fmaxf(sf[3][2], sf[3][3]));
        pm = fmaxf(fmaxf(a0, a1), fmaxf(a2, a3));
        pm = fmaxf(pm, __shfl_xor(pm, 16));
        pm = fmaxf(pm, __shfl_xor(pm, 32));
    }
    // defer-max: only rescale when some q-row's max grew (wave-uniform)
    if (!__all(pm <= mrow)) {
        const float mn = fmaxf(mrow, pm);
        const float corr = exp2f(mrow - mn);
        mrow = mn;
#pragma unroll
        for (int r = 0; r < 4; ++r) lacc[r] *= corr;
#pragma unroll
        for (int fd = 0; fd < 4; ++fd)
#pragma unroll
            for (int r = 0; r < 4; ++r) oacc[fd][r] *= corr;
    }
#pragma unroll
    for (int fn = 0; fn < 4; ++fn)
#pragma unroll
        for (int r = 0; r < 4; ++r) sf[fn][r] = exp2f(sf[fn][r] - mrow);
    int4 pw0, pw1;
    pw0.x = cvt_pk_bf16(sf[0][0], sf[0][1]);
    pw0.y = cvt_pk_bf16(sf[0][2], sf[0][3]);
    pw0.z = cvt_pk_bf16(sf[1][0], sf[1][1]);
    pw0.w = cvt_pk_bf16(sf[1][2], sf[1][3]);
    pw1.x = cvt_pk_bf16(sf[2][0], sf[2][1]);
    pw1.y = cvt_pk_bf16(sf[2][2], sf[2][3]);
    pw1.z = cvt_pk_bf16(sf[3][0], sf[3][1]);
    pw1.w = cvt_pk_bf16(sf[3][2], sf[3][3]);
    p0 = *(short8*)&pw0;
    p1 = *(short8*)&pw1;
}

// ---------------------------------------------------------------- attention (split-KV, 128q/block)
// Double-buffered K/Vt LDS: ONE barrier per 64-kv tile. Safety: iter kt
// writes buf=kt&1, whose last reader was iter kt-2; any wave at iter kt
// passed iter kt-1's barrier, which postdates iter kt-2's compute.
__launch_bounds__(256, 4)
__global__ void attn_split(const u16* __restrict__ Qb, const u16* __restrict__ Kb,
                           const u16* __restrict__ Vb, u16* __restrict__ Opart,
                           float2* __restrict__ ml) {
    __shared__ u16 Klds[2][64 * 72];
    __shared__ u16 Vt[2][64 * 72];
    const int tid = threadIdx.x;
    const int lane = tid & 63, w = tid >> 6;
    const int lr = lane & 15, lc = lane >> 4;
    const int b = blockIdx.y / NHEAD, h = blockIdx.y % NHEAD;
    const int z = blockIdx.z;
    const size_t qrowA = (size_t)b * TSEQ + blockIdx.x * 128 + w * 16;
    const size_t qrowB = qrowA + 64;
    const size_t krow0 = (size_t)b * TSEQ + (size_t)z * KVLEN;
    const int hc = h * 64;

    short8 qa0, qa1, qb0, qb1;
    {
        const u16* qp = Qb + (qrowA + lr) * CDIM + hc + lc * 8;
        qa0 = *(const short8*)qp;
        qa1 = *(const short8*)(qp + 32);
        const u16* qp2 = Qb + (qrowB + lr) * CDIM + hc + lc * 8;
        qb0 = *(const short8*)qp2;
        qb1 = *(const short8*)(qp2 + 32);
    }
    // ones A-fragment (bf16 1.0 in every slot) for the l-accumulation MFMAs
    short8 ones;
    {
        int4 ow = {0x3F803F80, 0x3F803F80, 0x3F803F80, 0x3F803F80};
        ones = *(short8*)&ow;
    }
    f32x4 oaccA[4], oaccB[4], laccA, laccB;
#pragma unroll
    for (int r = 0; r < 4; ++r) {
        oaccA[r] = (f32x4){0.f, 0.f, 0.f, 0.f};
        oaccB[r] = (f32x4){0.f, 0.f, 0.f, 0.f};
    }
    laccA = (f32x4){0.f, 0.f, 0.f, 0.f};
    laccB = (f32x4){0.f, 0.f, 0.f, 0.f};
    float mA = -3e38f, mB = -3e38f;

    const int stg_r = tid >> 2, stg_s = tid & 3;
    const u16* kg = Kb + (krow0 + stg_r) * CDIM + hc + stg_s * 16;
    const u16* vg = Vb + (krow0 + stg_r) * CDIM + hc + stg_s * 16;
    uint4 ka0 = *(const uint4*)kg, ka1 = *(const uint4*)(kg + 8);
    uint4 va0 = *(const uint4*)vg, va1 = *(const uint4*)(vg + 8);
    const int sig = ((stg_r >> 5) << 5) + (((stg_r >> 2) & 3) << 3) +
                    (((stg_r >> 4) & 1) << 2) + (stg_r & 3);
    char* vdst0 = (char*)Vt + ((2 * sig) ^ (stg_s << 5)) +
                  (size_t)(stg_s * 16) * 144;

    for (int kt = 0; kt < KVLEN / 64; ++kt) {
        const int buf = kt & 1;
        {   // write staged tile kt into LDS[buf] (no pre-barrier: see proof above)
            *(uint4*)&Klds[buf][stg_r * 72 + stg_s * 16]     = ka0;
            *(uint4*)&Klds[buf][stg_r * 72 + stg_s * 16 + 8] = ka1;
            u16 tmp[16];
            *(uint4*)(tmp)     = va0;
            *(uint4*)(tmp + 8) = va1;
            char* vd = vdst0 + (size_t)buf * (64 * 72 * 2);
#pragma unroll
            for (int j = 0; j < 16; ++j)
                *(u16*)(vd + (size_t)j * 144) = tmp[j];
        }
        if (kt < KVLEN / 64 - 1) {   // prefetch next tile into regs
            kg += 64 * CDIM; vg += 64 * CDIM;
            ka0 = *(const uint4*)kg; ka1 = *(const uint4*)(kg + 8);
            va0 = *(const uint4*)vg; va1 = *(const uint4*)(vg + 8);
        }
        __syncthreads();   // single barrier per tile

        // S^T = K * Q^T for both q-groups; each K fragment read used twice
        f32x4 sfA[4], sfB[4];
#pragma unroll
        for (int fn = 0; fn < 4; ++fn) {
            const u16* kr = &Klds[buf][(lr + fn * 16) * 72 + lc * 8];
            short8 kb0 = *(const short8*)kr;
            short8 kb1 = *(const short8*)(kr + 32);
            f32x4 t = (f32x4){0.f, 0.f, 0.f, 0.f};
            t = __builtin_amdgcn_mfma_f32_16x16x32_bf16(kb0, qa0, t, 0, 0, 0);
            t = __builtin_amdgcn_mfma_f32_16x16x32_bf16(kb1, qa1, t, 0, 0, 0);
            sfA[fn] = t;
            f32x4 u = (f32x4){0.f, 0.f, 0.f, 0.f};
            u = __builtin_amdgcn_mfma_f32_16x16x32_bf16(kb0, qb0, u, 0, 0, 0);
            u = __builtin_amdgcn_mfma_f32_16x16x32_bf16(kb1, qb1, u, 0, 0, 0);
            sfB[fn] = u;
        }

        short8 pA0, pA1, pB0, pB1;
        softmax_pack(sfA, mA, laccA, oaccA, pA0, pA1);
        softmax_pack(sfB, mB, laccB, oaccB, pB0, pB1);

        // l accumulation on the matrix pipe: D[r][q] = sum_k P[k][q]
        laccA = __builtin_amdgcn_mfma_f32_16x16x32_bf16(ones, pA0, laccA, 0, 0, 0);
        laccA = __builtin_amdgcn_mfma_f32_16x16x32_bf16(ones, pA1, laccA, 0, 0, 0);
        laccB = __builtin_amdgcn_mfma_f32_16x16x32_bf16(ones, pB0, laccB, 0, 0, 0);
        laccB = __builtin_amdgcn_mfma_f32_16x16x32_bf16(ones, pB1, laccB, 0, 0, 0);

        // O^T += V^T * P^T ; each V fragment read used twice
        const char* vbase = (const char*)Vt + (size_t)buf * (64 * 72 * 2);
#pragma unroll
        for (int fd = 0; fd < 4; ++fd) {
            const char* vtb = vbase + (size_t)(lr + fd * 16) * 144;
            short8 vb0 = *(const short8*)(vtb + ((lc * 16) ^ (fd * 32)));
            short8 vb1 = *(const short8*)(vtb + ((lc * 16 + 64) ^ (fd * 32)));
            oaccA[fd] = __builtin_amdgcn_mfma_f32_16x16x32_bf16(vb0, pA0, oaccA[fd], 0, 0, 0);
            oaccA[fd] = __builtin_amdgcn_mfma_f32_16x16x32_bf16(vb1, pA1, oaccA[fd], 0, 0, 0);
            oaccB[fd] = __builtin_amdgcn_mfma_f32_16x16x32_bf16(vb0, pB0, oaccB[fd], 0, 0, 0);
            oaccB[fd] = __builtin_amdgcn_mfma_f32_16x16x32_bf16(vb1, pB1, oaccB[fd], 0, 0, 0);
        }
    }

    // epilogue: UNNORMALIZED bf16 partials + (m,l) for both groups.
    // lacc rows are all equal: l[q=lr] = lacc[any r].
    u16* oA = Opart + (size_t)z * NROWS * CDIM + (qrowA + lr) * CDIM + hc + lc * 4;
    u16* oB = Opart + (size_t)z * NROWS * CDIM + (qrowB + lr) * CDIM + hc + lc * 4;
#pragma unroll
    for (int fd = 0; fd < 4; ++fd) {
        ushort4 o;
        o.x = f2bf(oaccA[fd][0]); o.y = f2bf(oaccA[fd][1]);
        o.z = f2bf(oaccA[fd][2]); o.w = f2bf(oaccA[fd][3]);
        *(ushort4*)(oA + fd * 16) = o;
        o.x = f2bf(oaccB[fd][0]); o.y = f2bf(oaccB[fd][1]);
        o.z = f2bf(oaccB[fd][2]); o.w = f2bf(oaccB[fd][3]);
        *(ushort4*)(oB + fd * 16) = o;
    }
    if (lc == 0) {
        ml[((size_t)z * NROWS + qrowA + lr) * NHEAD + h] = (float2){mA, laccA[0]};
        ml[((size_t)z * NROWS + qrowB + lr) * NHEAD + h] = (float2){mB, laccB[0]};
    }
}

// ---------------------------------------------------------------- merge (4 parts)
__launch_bounds__(256)
__global__ void attn_merge4(const u16* __restrict__ P, const float2* __restrict__ ml,
                            u16* __restrict__ out) {
    const int i4 = blockIdx.x * 256 + threadIdx.x;   // 4-elem chunk index
    const size_t base = (size_t)i4 * 4;
    const int row = (int)(base / CDIM);
    const int head = (int)(base - (size_t)row * CDIM) >> 6;
    float2 a[KVSPLIT];
    float M = -3e38f;
#pragma unroll
    for (int z = 0; z < KVSPLIT; ++z) {
        a[z] = ml[((size_t)z * NROWS + row) * NHEAD + head];
        M = fmaxf(M, a[z].x);
    }
    float den = 0.f, e[KVSPLIT];
#pragma unroll
    for (int z = 0; z < KVSPLIT; ++z) {
        e[z] = exp2f(a[z].x - M);
        den += a[z].y * e[z];
    }
    const float rden = 1.f / den;
    float o0 = 0.f, o1 = 0.f, o2 = 0.f, o3 = 0.f;
#pragma unroll
    for (int z = 0; z < KVSPLIT; ++z) {
        ushort4 p = *(const ushort4*)(P + (size_t)z * NROWS * CDIM + base);
        o0 += bf2f(p.x) * e[z];
        o1 += bf2f(p.y) * e[z];
        o2 += bf2f(p.z) * e[z];
        o3 += bf2f(p.w) * e[z];
    }
    ushort4 o;
    o.x = f2bf(o0 * rden); o.y = f2bf(o1 * rden);
    o.z = f2bf(o2 * rden); o.w = f2bf(o3 * rden);
    *(ushort4*)(out + base) = o;
}

// ---------------------------------------------------------------- launch
extern "C" void kernel_launch(void* const* d_in, const int* in_sizes, int n_in,
                              void* d_out, int out_size, void* d_ws, size_t ws_size,
                              hipStream_t stream) {
    const float* x     = (const float*)d_in[0];
    const float* ctx   = (const float*)d_in[1];
    const float* ln1g  = (const float*)d_in[2];
    const float* ln1b  = (const float*)d_in[3];
    const float* ln2g  = (const float*)d_in[4];
    const float* ln2b  = (const float*)d_in[5];
    const float* ln3g  = (const float*)d_in[6];
    const float* ln3b  = (const float*)d_in[7];
    const float* sa_wq = (const float*)d_in[8];
    const float* sa_bq = (const float*)d_in[9];
    const float* sa_wk = (const float*)d_in[10];
    const float* sa_bk = (const float*)d_in[11];
    const float* sa_wv = (const float*)d_in[12];
    const float* sa_bv = (const float*)d_in[13];
    const float* sa_wo = (const float*)d_in[14];
    const float* sa_bo = (const float*)d_in[15];
    const float* xa_wq = (const float*)d_in[16];
    const float* xa_bq = (const float*)d_in[17];
    const float* xa_wk = (const float*)d_in[18];
    const float* xa_bk = (const float*)d_in[19];
    const float* xa_wv = (const float*)d_in[20];
    const float* xa_bv = (const float*)d_in[21];
    const float* xa_wo = (const float*)d_in[22];
    const float* xa_bo = (const float*)d_in[23];
    const float* m_w1  = (const float*)d_in[24];
    const float* m_b1  = (const float*)d_in[25];
    const float* m_w2  = (const float*)d_in[26];
    const float* m_b2  = (const float*)d_in[27];

    float* out_x   = (float*)d_out;
    float* out_ctx = out_x + (size_t)NROWS * CDIM;
    // d_out doubles as scratch: bf16 split-KV partials during attention,
    // then m_w2^T (4.7MB, in the out_ctx half) during the MLP. The ctx
    // passthrough memcpy is the LAST op.
    u16* Opart = (u16*)d_out;
    u16* W2s   = (u16*)out_ctx;

    const size_t SZ_ACT  = (size_t)NROWS * CDIM * 2;
    const size_t SZ_WBIG = (size_t)HDIM * CDIM * 2;
    const size_t SZ_R    = (size_t)NROWS * CDIM * 4;
    const size_t NEEDED  = 5 * SZ_ACT + SZ_R + SZ_WBIG;
    if (ws_size < NEEDED) return;

    char* ws = (char*)d_ws;
    u16* qb    = (u16*)(ws);
    u16* kb    = (u16*)(ws + 1 * SZ_ACT);
    u16* vb    = (u16*)(ws + 2 * SZ_ACT);
    u16* ctxb  = (u16*)(ws + 3 * SZ_ACT);
    u16* hb    = qb;
    u16* lnbuf = (u16*)(ws + 4 * SZ_ACT);
    u16* attB  = lnbuf;
    float* R   = (float*)(ws + 5 * SZ_ACT);
    u16* Wq    = (u16*)(ws + 5 * SZ_ACT + SZ_R);   // pool: [Wq][Wk][Wv][Wo]
    u16* Wk    = Wq + (size_t)CDIM * CDIM;
    u16* Wv    = Wk + (size_t)CDIM * CDIM;
    u16* Wo    = Wv + (size_t)CDIM * CDIM;
    // ml (1.57MB) overlays Wq+Wk (dead after the QKV GEMM); Wo survives.
    float2* ml = (float2*)Wq;

    const dim3 tb(256);
    GemmArgs ga;

    // ---- self-attention
    Pre1 p1;
    p1.ctx = ctx; p1.ctxb = ctxb;
    p1.x = x; p1.g = ln1g; p1.bta = ln1b; p1.lnout = lnbuf;
    p1.w[0] = sa_wq; p1.w[1] = sa_wk; p1.w[2] = sa_wv; p1.w[3] = sa_wo;
    p1.wt[0] = Wq;   p1.wt[1] = Wk;   p1.wt[2] = Wv;   p1.wt[3] = Wo;
    pre1_kernel<<<dim3(3072 + 4096 + 2304), tb, 0, stream>>>(p1);
    ga = GemmArgs{};
    ga.A[0] = lnbuf; ga.BT[0] = Wq; ga.bias[0] = sa_bq; ga.out[0] = qb; ga.alpha[0] = QSCALE;
    ga.A[1] = lnbuf; ga.BT[1] = Wk; ga.bias[1] = sa_bk; ga.out[1] = kb; ga.alpha[1] = 1.f;
    ga.A[2] = lnbuf; ga.BT[2] = Wv; ga.bias[2] = sa_bv; ga.out[2] = vb; ga.alpha[2] = 1.f;
    ga.M = 4096; ga.N = 768; ga.K = 768;
    gemm_bt<0, 128, 64><<<dim3(32, 12, 3), tb, 0, stream>>>(ga);
    attn_split<<<dim3(16, 24, KVSPLIT), tb, 0, stream>>>(qb, kb, vb, Opart, ml);
    attn_merge4<<<dim3(NROWS * CDIM / 1024), tb, 0, stream>>>(Opart, ml, attB);
    ga = GemmArgs{};
    ga.A[0] = attB; ga.BT[0] = Wo; ga.bias[0] = sa_bo; ga.res[0] = x; ga.out[0] = R; ga.alpha[0] = 1.f;
    ga.M = 4096; ga.N = 768; ga.K = 768;
    gemm_bt<1, 64, 64><<<dim3(64, 12, 1), tb, 0, stream>>>(ga);

    // ---- cross-attention
    Pre2 p2;
    p2.x = R; p2.g = ln2g; p2.bta = ln2b; p2.lnout = lnbuf;
    p2.w[0] = xa_wq; p2.w[1] = xa_wk; p2.w[2] = xa_wv; p2.w[3] = xa_wo;
    p2.wt[0] = Wq;   p2.wt[1] = Wk;   p2.wt[2] = Wv;   p2.wt[3] = Wo;
    pre2_kernel<<<dim3(4096 + 2304), tb, 0, stream>>>(p2);
    ga = GemmArgs{};
    ga.A[0] = lnbuf; ga.BT[0] = Wq; ga.bias[0] = xa_bq; ga.out[0] = qb; ga.alpha[0] = QSCALE;
    ga.A[1] = ctxb;  ga.BT[1] = Wk; ga.bias[1] = xa_bk; ga.out[1] = kb; ga.alpha[1] = 1.f;
    ga.A[2] = ctxb;  ga.BT[2] = Wv; ga.bias[2] = xa_bv; ga.out[2] = vb; ga.alpha[2] = 1.f;
    ga.M = 4096; ga.N = 768; ga.K = 768;
    gemm_bt<0, 128, 64><<<dim3(32, 12, 3), tb, 0, stream>>>(ga);
    attn_split<<<dim3(16, 24, KVSPLIT), tb, 0, stream>>>(qb, kb, vb, Opart, ml);
    attn_merge4<<<dim3(NROWS * CDIM / 1024), tb, 0, stream>>>(Opart, ml, attB);
    ga = GemmArgs{};
    ga.A[0] = attB; ga.BT[0] = Wo; ga.bias[0] = xa_bo; ga.res[0] = R; ga.out[0] = R; ga.alpha[0] = 1.f;
    ga.M = 4096; ga.N = 768; ga.K = 768;
    gemm_bt<1, 64, 64><<<dim3(64, 12, 1), tb, 0, stream>>>(ga);

    // ---- MLP (m_w2^T staged in the dead out_ctx half of d_out)
    Pre3 p3;
    p3.x = R; p3.g = ln3g; p3.bta = ln3b; p3.lnout = lnbuf;
    p3.w1 = m_w1; p3.wt1 = Wq;
    p3.w2 = m_w2; p3.wt2 = W2s;
    pre3_kernel<<<dim3(4096 + 2304 + 2304), tb, 0, stream>>>(p3);
    ga = GemmArgs{};
    ga.A[0] = lnbuf; ga.BT[0] = Wq; ga.bias[0] = m_b1; ga.out[0] = hb; ga.alpha[0] = 1.f;
    ga.M = 4096; ga.N = 3072; ga.K = 768;
    gemm_bt<2, 128><<<dim3(32, 24, 1), tb, 0, stream>>>(ga);
    ga = GemmArgs{};
    ga.A[0] = hb; ga.BT[0] = W2s; ga.bias[0] = m_b2; ga.res[0] = R; ga.out[0] = out_x; ga.alpha[0] = 1.f;
    ga.M = 4096; ga.N = 768; ga.K = 3072;
    gemm_bt<1, 64, 64><<<dim3(64, 12, 1), tb, 0, stream>>>(ga);
    // context passthrough LAST (d_out scratch roles all expired)
    hipMemcpyAsync(out_ctx, ctx, (size_t)NROWS * CDIM * 4,
                   hipMemcpyDeviceToDevice, stream);

    (void)in_sizes; (void)n_in; (void)out_size;
}